// Round 1
// baseline (292.153 us; speedup 1.0000x reference)
//
#include <hip/hip_runtime.h>
#include <math.h>

// Geometry: features [B=8,C=256,H=64,W=64]; outputs [8,2,256,256]
#define HWPX  4096
#define CCH   256
#define NPIX  32768
#define NCHAN 2048
#define NFEAT 8388608

// Workspace layout (floats). Every cell written before read except CNT,
// which is armed by a 4-byte hipMemsetAsync before the kernel.
#define A1P_OFF   0                         // 4q x 8slices x NPIX (A1 partials)
#define A2P_OFF   (A1P_OFF + 4*8*NPIX)      // 5q x 8slices x NPIX (A2 partials)
#define CHS_OFF   (A2P_OFF + 5*8*NPIX)      // 2048 bc x 16 slots (4 wdw x 4 waves)
#define CHT_OFF   (CHS_OFF + NCHAN*16)
#define KLP_OFF   (CHT_OFF + NCHAN*16)      // 512 block partials (KL)
#define CL1_OFF   (KLP_OFF + 512)
#define GP0_OFF   (CL1_OFF + 512)           // 128 (C1 phase partials)
#define GP1_OFF   (GP0_OFF + 128)
#define GP2_OFF   (GP1_OFF + 128)
#define DTP_OFF   (GP2_OFF + 128)           // 128 (C2D phase partials)
#define STP_OFF   (DTP_OFF + 128)
#define CFP_OFF   (STP_OFF + 128)
#define CAP_OFF   (CFP_OFF + 128)
#define CNT_OFF   (CAP_OFF + 128)           // progress counter (memset to 0)

#define NBLK  1024u
#define NWORK 128u

// s_waitcnt with vmcnt(N), lgkm/exp unconstrained (gfx9 encoding)
#define WAITVM(N) __builtin_amdgcn_s_waitcnt(0xF70 | (N))

__device__ __forceinline__ void async16(const float* g, float* l) {
  __builtin_amdgcn_global_load_lds(
      (const __attribute__((address_space(1))) void*)g,
      (__attribute__((address_space(3))) void*)l, 16, 0, 0);
}

__device__ __forceinline__ float sigmoidf_(float x) { return 1.0f / (1.0f + expf(-x)); }

__device__ __forceinline__ float wred(float v) {
#pragma unroll
  for (int o = 32; o > 0; o >>= 1) v += __shfl_down(v, o, 64);
  return v;
}

__device__ __forceinline__ void upd1(const float4& A, const float4& B, const float4& C,
                                     float4& l2a, float4& ca, float4& l2b, float4& cb)
{
#define U1(K) { \
  float d = A.K - B.K; l2a.K = fmaf(d, d, l2a.K); \
  float p = A.K * B.K; \
  float den = fmaxf(fabsf(A.K) * fabsf(B.K), 1e-8f); \
  ca.K = fmaf(p, __builtin_amdgcn_rcpf(den), ca.K); \
  float d2 = A.K - C.K; l2b.K = fmaf(d2, d2, l2b.K); \
  float p2 = A.K * C.K; \
  float dn2 = fmaxf(fabsf(A.K) * fabsf(C.K), 1e-8f); \
  cb.K = fmaf(p2, __builtin_amdgcn_rcpf(dn2), cb.K); }
  U1(x) U1(y) U1(z) U1(w)
#undef U1
}

__device__ __forceinline__ void upd2(const float4& S, const float4& T,
                                     float4& ssq, float4& ssm, float4& smx,
                                     float4& tsm, float4& tmx)
{
#define U2(K) { \
  float ds = S.K - T.K; ssq.K = fmaf(ds, ds, ssq.K); \
  ssm.K += S.K; tsm.K += T.K; \
  smx.K = fmaxf(smx.K, S.K); tmx.K = fmaxf(tmx.K, T.K); }
  U2(x) U2(y) U2(z) U2(w)
#undef U2
}

// ---------- Fused kernel: phase-1 (A1|A2|KL) + ticketed C1/C2D tail ----------
// Phase 1 is identical to the proven kernBIG. After phase-1 stores each block
// release-fences (buffer_wbl2) and draws a ticket from CNT. The LAST 128
// finishers become workers: spin to 1024 (all phase-1 visible), acquire-fence
// (buffer_inv), then do the C1 combine for their 256-px slice keeping the
// per-pixel maps IN REGISTERS (the OPTD/HETD/SSP/TSP arrays are gone). A
// second counter level (1152) gates the mean-dependent C2D phase; the last
// worker (prev==1279) performs the final combine.
// Deadlock-safe: 48KB LDS -> 3 blocks/CU -> 768 resident slots >> 128 max
// spinners, so non-spinner blocks always retire and the counter advances.
__global__ __launch_bounds__(256) void kernALL(
    const float* __restrict__ o1p, const float* __restrict__ o2p,
    const float* __restrict__ srp,
    const float* __restrict__ stu, const float* __restrict__ tea,
    const float* __restrict__ so,  const float* __restrict__ to,
    const float* __restrict__ mk,
    float* __restrict__ ws, float* __restrict__ out)
{
  const int bid = blockIdx.x;
  const int tid = threadIdx.x, lane = tid & 63, w = tid >> 6;
  __shared__ float sb[4][3][1024];   // 48 KB staging; aliased as scratch later
  __shared__ unsigned tk_s;
  __shared__ bool isLast;

  // ============================ phase 1 ============================
  if (bid < 256) {
    // ---------------- A1: diff maps ----------------
    const int b   = bid >> 5;
    const int r   = bid & 31;
    const int wdw = r >> 3;
    const int cs  = r & 7;
    const int c0  = cs * 32;
    const size_t base = ((size_t)(b * CCH + c0)) * HWPX + wdw * 1024 + lane * 4;
    const int wo = w * 256;

#define STAGE1(d, step) { \
    const size_t o = base + (size_t)(step) * HWPX; \
    async16(o1p + o, &sb[d][0][wo]); \
    async16(o2p + o, &sb[d][1][wo]); \
    async16(srp + o, &sb[d][2][wo]); }

    STAGE1(0, 0) STAGE1(1, 1) STAGE1(2, 2) STAGE1(3, 3)

    float4 l2a = {0,0,0,0}, ca = {0,0,0,0}, l2b = {0,0,0,0}, cb = {0,0,0,0};
    for (int s = 0; s < 32; ++s) {
      const int d = s & 3;
      if (s <= 28)      WAITVM(9);
      else if (s == 29) WAITVM(6);
      else if (s == 30) WAITVM(3);
      else              WAITVM(0);
      __builtin_amdgcn_sched_barrier(0);
      const float4 Av = *(const float4*)&sb[d][0][tid * 4];
      const float4 Bv = *(const float4*)&sb[d][1][tid * 4];
      const float4 Cv = *(const float4*)&sb[d][2][tid * 4];
      upd1(Av, Bv, Cv, l2a, ca, l2b, cb);
      if (s + 4 < 32) STAGE1(d, s + 4);
    }
#undef STAGE1

    const int gp4 = b * HWPX + wdw * 1024 + tid * 4;
    float* pa = ws + A1P_OFF;
    *(float4*)&pa[(0 * 8 + cs) * NPIX + gp4] = l2a;
    *(float4*)&pa[(1 * 8 + cs) * NPIX + gp4] = ca;
    *(float4*)&pa[(2 * 8 + cs) * NPIX + gp4] = l2b;
    *(float4*)&pa[(3 * 8 + cs) * NPIX + gp4] = cb;

  } else if (bid < 512) {
    // ---------------- A2: student/teacher stats + channel sums ----------------
    const int bidA = bid - 256;
    const int b   = bidA >> 5;
    const int r   = bidA & 31;
    const int wdw = r >> 3;
    const int cs  = r & 7;
    const int c0  = cs * 32;
    const size_t base = ((size_t)(b * CCH + c0)) * HWPX + wdw * 1024 + lane * 4;
    const int wo = w * 256;

#define STAGE2(d, step) { \
    const size_t o = base + (size_t)(step) * HWPX; \
    async16(stu + o, &sb[d][0][wo]); \
    async16(tea + o, &sb[d][1][wo]); }

    STAGE2(0, 0) STAGE2(1, 1) STAGE2(2, 2) STAGE2(3, 3)

    float4 ssq = {0,0,0,0}, ssm = {0,0,0,0}, tsm = {0,0,0,0};
    float4 smx = {-INFINITY,-INFINITY,-INFINITY,-INFINITY};
    float4 tmx = smx;
    for (int s = 0; s < 32; ++s) {
      const int d = s & 3;
      if (s <= 28)      WAITVM(6);
      else if (s == 29) WAITVM(4);
      else if (s == 30) WAITVM(2);
      else              WAITVM(0);
      __builtin_amdgcn_sched_barrier(0);
      const float4 Sv = *(const float4*)&sb[d][0][tid * 4];
      const float4 Tv = *(const float4*)&sb[d][1][tid * 4];
      upd2(Sv, Tv, ssq, ssm, smx, tsm, tmx);
      float csm = (Sv.x + Sv.y) + (Sv.z + Sv.w);
      float ctm = (Tv.x + Tv.y) + (Tv.z + Tv.w);
      csm = wred(csm); ctm = wred(ctm);
      if (lane == 0) {
        const int bc = b * CCH + c0 + s;
        ws[CHS_OFF + bc * 16 + wdw * 4 + w] = csm;
        ws[CHT_OFF + bc * 16 + wdw * 4 + w] = ctm;
      }
      if (s + 4 < 32) STAGE2(d, s + 4);
    }
#undef STAGE2

    const int gp4 = b * HWPX + wdw * 1024 + tid * 4;
    float* pa = ws + A2P_OFF;
    *(float4*)&pa[(0 * 8 + cs) * NPIX + gp4] = ssq;
    *(float4*)&pa[(1 * 8 + cs) * NPIX + gp4] = ssm;
    *(float4*)&pa[(2 * 8 + cs) * NPIX + gp4] = smx;
    *(float4*)&pa[(3 * 8 + cs) * NPIX + gp4] = tsm;
    *(float4*)&pa[(4 * 8 + cs) * NPIX + gp4] = tmx;

  } else {
    // ---------------- KL: 2-way softmax KL + class1 MSE ----------------
    const int bkl = bid - 512;
    const int gid = bkl * 256 + tid;
    const int p4 = gid << 2;
    const int b  = p4 >> 16;
    const int pp = p4 & 65535;
    const int i0 = b * 131072 + pp;

    const float4 s0 = *(const float4*)(so + i0);
    const float4 s1 = *(const float4*)(so + i0 + 65536);
    const float4 t0 = *(const float4*)(to + i0);
    const float4 t1 = *(const float4*)(to + i0 + 65536);

    float kl = 0.f, c1 = 0.f;
#define KLC(S0, S1, T0, T1)                                           \
    {                                                                 \
      float xs = (S1 - S0) * 0.25f;                                   \
      float xt = (T1 - T0) * 0.25f;                                   \
      float lzs = fmaxf(xs, 0.f) + log1pf(expf(-fabsf(xs)));          \
      float lzt = fmaxf(xt, 0.f) + log1pf(expf(-fabsf(xt)));          \
      float ls0 = -lzs, ls1 = xs - lzs;                               \
      float lt0 = -lzt, lt1 = xt - lzt;                               \
      float pt0 = expf(lt0), pt1 = expf(lt1);                         \
      kl += pt0 * (lt0 - ls0) + pt1 * (lt1 - ls1);                    \
      float ps1 = expf(ls1);                                          \
      float dd = ps1 - pt1;                                           \
      c1 += dd * dd;                                                  \
    }
    KLC(s0.x, s1.x, t0.x, t1.x)
    KLC(s0.y, s1.y, t0.y, t1.y)
    KLC(s0.z, s1.z, t0.z, t1.z)
    KLC(s0.w, s1.w, t0.w, t1.w)
#undef KLC

    kl = wred(kl);
    c1 = wred(c1);
    if ((tid & 63) == 0) { sb[0][0][w * 2] = kl; sb[0][0][w * 2 + 1] = c1; }
    __syncthreads();
    if (tid == 0) {
      ws[KLP_OFF + bkl] = sb[0][0][0] + sb[0][0][2] + sb[0][0][4] + sb[0][0][6];
      ws[CL1_OFF + bkl] = sb[0][0][1] + sb[0][0][3] + sb[0][0][5] + sb[0][0][7];
    }
  }

  // ============================ ticket ============================
  __syncthreads();                   // compiler drains vmcnt before s_barrier
  unsigned* cnt = (unsigned*)(ws + CNT_OFF);
  if (tid == 0) {
    __threadfence();                 // agent release: wbl2 block's stores to LLC
    tk_s = __hip_atomic_fetch_add(cnt, 1u, __ATOMIC_ACQ_REL,
                                  __HIP_MEMORY_SCOPE_AGENT);
  }
  __syncthreads();
  const unsigned ticket = tk_s;
  if (ticket < NBLK - NWORK) return;           // only the last 128 continue
  const int slice = (int)(ticket - (NBLK - NWORK));   // 0..127

  if (tid == 0) {
    while (__hip_atomic_load(cnt, __ATOMIC_RELAXED,
                             __HIP_MEMORY_SCOPE_AGENT) < NBLK)
      __builtin_amdgcn_s_sleep(1);
  }
  __syncthreads();
  __threadfence();                   // acquire: invalidate L1/L2, read fresh LLC

  // ====================== C1: cross-slice combine ======================
  const int gp = slice * 256 + tid;
  const float* pA = ws + A1P_OFF;
  const float* pB = ws + A2P_OFF;

  float a0 = 0.f, a1 = 0.f, a2 = 0.f, a3 = 0.f;
  float b0 = 0.f, b1 = 0.f, b3 = 0.f;
  float m2 = -INFINITY, m4 = -INFINITY;
#pragma unroll
  for (int s = 0; s < 8; ++s) {
    a0 += pA[(0 * 8 + s) * NPIX + gp];
    a1 += pA[(1 * 8 + s) * NPIX + gp];
    a2 += pA[(2 * 8 + s) * NPIX + gp];
    a3 += pA[(3 * 8 + s) * NPIX + gp];
    b0 += pB[(0 * 8 + s) * NPIX + gp];
    b1 += pB[(1 * 8 + s) * NPIX + gp];
    m2 = fmaxf(m2, pB[(2 * 8 + s) * NPIX + gp]);
    b3 += pB[(3 * 8 + s) * NPIX + gp];
    m4 = fmaxf(m4, pB[(4 * 8 + s) * NPIX + gp]);
  }

  // per-pixel maps stay in registers for the C2D phase (no global maps)
  const float l2o = sqrtf(a0 + 1e-6f);
  const float od  = (l2o + 1.0f - a1 * (1.0f / 256.0f)) * sigmoidf_(l2o * 5.0f);
  const float l2h = sqrtf(a2 + 1e-6f);
  const float hd  = (l2h + 1.0f - a3 * (1.0f / 256.0f)) * sigmoidf_(l2h * 5.0f);
  const float ssp = sigmoidf_(b1 * (1.0f / 256.0f) + m2);
  const float tsp = sigmoidf_(b3 * (1.0f / 256.0f) + m4);

  const float mv = mk[gp];
  float r0 = b0, r1 = mv * mv * b0, r2 = od;
  r0 = wred(r0); r1 = wred(r1); r2 = wred(r2);
  float* red = &sb[0][0][0];                 // [4][3] scratch alias
  if ((tid & 63) == 0) { red[w * 3 + 0] = r0; red[w * 3 + 1] = r1; red[w * 3 + 2] = r2; }
  __syncthreads();
  if (tid == 0) {
    ws[GP0_OFF + slice] = red[0] + red[3] + red[6] + red[9];
    ws[GP1_OFF + slice] = red[1] + red[4] + red[7] + red[10];
    ws[GP2_OFF + slice] = red[2] + red[5] + red[8] + red[11];
    __threadfence();
    __hip_atomic_fetch_add(cnt, 1u, __ATOMIC_ACQ_REL, __HIP_MEMORY_SCOPE_AGENT);
    while (__hip_atomic_load(cnt, __ATOMIC_RELAXED,
                             __HIP_MEMORY_SCOPE_AGENT) < NBLK + NWORK)
      __builtin_amdgcn_s_sleep(1);
  }
  __syncthreads();
  __threadfence();                   // acquire for GP2 written by other workers

  // ====================== C2D: mean-dependent terms ======================
  float v = (tid < 128) ? ws[GP2_OFF + tid] : 0.f;
  v = wred(v);
  float* smo = &sb[0][1][0];                 // [4] scratch alias
  if ((tid & 63) == 0) smo[w] = v;
  __syncthreads();
  const float mean_opt = (smo[0] + smo[1] + smo[2] + smo[3]) * (1.0f / 32768.0f);
  const float att_w = sigmoidf_(mean_opt * 10.0f);
  const float thr = mean_opt * 1.5f;

  const float mask = od > thr ? 1.0f : 0.0f;
  const float wgt = mask * 2.0f + (1.0f - mask) * 0.5f;
  float dt = (hd - od) * wgt; dt *= dt;
  const float amp = 1.0f + att_w * mask;
  float st = (ssp - tsp) * amp; st *= st;

  float cf = 0.f, catt = 0.f;
  if (gp < NCHAN) {
    float s = 0.f, t = 0.f;
#pragma unroll
    for (int k = 0; k < 16; ++k) {
      s += ws[CHS_OFF + gp * 16 + k];
      t += ws[CHT_OFF + gp * 16 + k];
    }
    const float smn = s * (1.0f / 4096.0f);
    const float tmn = t * (1.0f / 4096.0f);
    const float d = smn - tmn;
    cf = d * d;
    const float d2 = sigmoidf_(smn) - sigmoidf_(tmn);
    catt = d2 * d2;
  }

  dt = wred(dt); st = wred(st); cf = wred(cf); catt = wred(catt);
  float* red2 = &sb[0][2][0];                // [4][4] scratch alias
  if ((tid & 63) == 0) {
    red2[w * 4 + 0] = dt; red2[w * 4 + 1] = st;
    red2[w * 4 + 2] = cf; red2[w * 4 + 3] = catt;
  }
  __syncthreads();
  if (tid == 0) {
    __hip_atomic_store(ws + DTP_OFF + slice,
                       red2[0] + red2[4] + red2[8]  + red2[12],
                       __ATOMIC_RELAXED, __HIP_MEMORY_SCOPE_AGENT);
    __hip_atomic_store(ws + STP_OFF + slice,
                       red2[1] + red2[5] + red2[9]  + red2[13],
                       __ATOMIC_RELAXED, __HIP_MEMORY_SCOPE_AGENT);
    __hip_atomic_store(ws + CFP_OFF + slice,
                       red2[2] + red2[6] + red2[10] + red2[14],
                       __ATOMIC_RELAXED, __HIP_MEMORY_SCOPE_AGENT);
    __hip_atomic_store(ws + CAP_OFF + slice,
                       red2[3] + red2[7] + red2[11] + red2[15],
                       __ATOMIC_RELAXED, __HIP_MEMORY_SCOPE_AGENT);
    __threadfence();
    unsigned prev = __hip_atomic_fetch_add(cnt, 1u, __ATOMIC_ACQ_REL,
                                           __HIP_MEMORY_SCOPE_AGENT);
    isLast = (prev == NBLK + 2u * NWORK - 1u);
  }
  __syncthreads();
  if (!isLast) return;
  __threadfence();

  // ---- last worker performs the final combine ----
  float* sm = &sb[1][0][0];                  // [4] scratch alias
  auto bsum = [&](int off, int n) -> float {
    float acc = 0.f;
    for (int i = tid; i < n; i += 256)
      acc += __hip_atomic_load(ws + off + i, __ATOMIC_RELAXED, __HIP_MEMORY_SCOPE_AGENT);
    acc = wred(acc);
    if ((tid & 63) == 0) sm[tid >> 6] = acc;
    __syncthreads();
    const float r = sm[0] + sm[1] + sm[2] + sm[3];
    __syncthreads();
    return r;
  };

  const float ssqg = bsum(GP0_OFF, 128);
  const float ssql = bsum(GP1_OFF, 128);
  const float sopt = bsum(GP2_OFF, 128);
  const float kls  = bsum(KLP_OFF, 512);
  const float c1s  = bsum(CL1_OFF, 512);
  const float dts  = bsum(DTP_OFF, 128);
  const float sts  = bsum(STP_OFF, 128);
  const float cfs  = bsum(CFP_OFF, 128);
  const float cas  = bsum(CAP_OFF, 128);

  if (tid == 0) {
    const float global_loss = ssqg * (1.0f / (float)NFEAT);
    const float local_loss  = ssql * (1.0f / (float)NFEAT);
    const float chan_f      = cfs * (1.0f / (float)NCHAN);
    const float feat = 0.3f * global_loss + 0.5f * local_loss + 0.2f * chan_f;

    const float kl = kls * 2.0f;                 // * T^2 / B = 16/8
    const float c1 = c1s * (2.0f / 524288.0f);
    const float outl = kl + c1;

    const float mo = sopt * (1.0f / 32768.0f);
    const float aw = sigmoidf_(mo * 10.0f);
    const float diff_loss = dts * (1.0f / 32768.0f);
    const float spat_loss = sts * (1.0f / 32768.0f);
    const float chan_att  = cas * (1.0f / (float)NCHAN);

    const float alpha = 0.5f * (1.0f + 0.5f * aw);
    const float beta  = 0.3f * (1.0f - 0.3f * aw);
    const float gamma = 0.2f * (1.0f + 0.5f * aw);
    const float datt = alpha * diff_loss + beta * chan_att + gamma * spat_loss;

    const float total = 0.3f * feat + 0.4f * outl + 0.3f * datt;
    out[0] = total;
    out[1] = feat;
    out[2] = outl;
    out[3] = datt;
  }
}

extern "C" void kernel_launch(void* const* d_in, const int* in_sizes, int n_in,
                              void* d_out, int out_size, void* d_ws, size_t ws_size,
                              hipStream_t stream)
{
  const float* stu = (const float*)d_in[0];
  const float* tea = (const float*)d_in[1];
  const float* so  = (const float*)d_in[2];
  const float* to  = (const float*)d_in[3];
  const float* o1  = (const float*)d_in[4];
  const float* o2  = (const float*)d_in[5];
  const float* sr  = (const float*)d_in[6];
  const float* mk  = (const float*)d_in[7];
  float* ws  = (float*)d_ws;
  float* out = (float*)d_out;

  // arm the progress counter (graph-capturable), then one fused dispatch
  hipMemsetAsync((void*)(ws + CNT_OFF), 0, sizeof(unsigned), stream);
  kernALL<<<1024, 256, 0, stream>>>(o1, o2, sr, stu, tea, so, to, mk, ws, out);
}

// Round 2
// 250.856 us; speedup vs baseline: 1.1646x; 1.1646x over previous
//
#include <hip/hip_runtime.h>
#include <math.h>

// Geometry: features [B=8,C=256,H=64,W=64]; outputs [8,2,256,256]
#define HWPX  4096
#define CCH   256
#define NPIX  32768
#define NCHAN 2048
#define NFEAT 8388608

// Workspace layout (floats). Every cell written before read; no memset.
#define A1P_OFF   0                         // 4q x 8slices x NPIX (A1 partials)
#define A2P_OFF   (A1P_OFF + 4*8*NPIX)      // 5q x 8slices x NPIX (A2 partials)
#define CHS_OFF   (A2P_OFF + 5*8*NPIX)      // 2048 bc x 16 slots (4 wdw x 4 waves)
#define CHT_OFF   (CHS_OFF + NCHAN*16)
#define OPTD_OFF  (CHT_OFF + NCHAN*16)      // 32768 per-pixel maps
#define HETD_OFF  (OPTD_OFF + NPIX)
#define SSP_OFF   (HETD_OFF + NPIX)
#define TSP_OFF   (SSP_OFF + NPIX)
#define KLP_OFF   (TSP_OFF + NPIX)          // 512 block partials (KL)
#define CL1_OFF   (KLP_OFF + 512)
#define GP0_OFF   (CL1_OFF + 512)           // 128 (kernC1)
#define GP1_OFF   (GP0_OFF + 128)
#define GP2_OFF   (GP1_OFF + 128)
#define DTP_OFF   (GP2_OFF + 128)           // 128 (kernC2D)
#define STP_OFF   (DTP_OFF + 128)
#define CFP_OFF   (STP_OFF + 128)
#define CAP_OFF   (CFP_OFF + 128)
#define CNT_OFF   (CAP_OFF + 128)           // completion counter (armed by C1)

__device__ __forceinline__ float sigmoidf_(float x) { return 1.0f / (1.0f + expf(-x)); }

__device__ __forceinline__ float wred(float v) {
#pragma unroll
  for (int o = 32; o > 0; o >>= 1) v += __shfl_down(v, o, 64);
  return v;
}

__device__ __forceinline__ void upd1(const float4& A, const float4& B, const float4& C,
                                     float4& l2a, float4& ca, float4& l2b, float4& cb)
{
#define U1(K) { \
  float d = A.K - B.K; l2a.K = fmaf(d, d, l2a.K); \
  float p = A.K * B.K; \
  float den = fmaxf(fabsf(A.K) * fabsf(B.K), 1e-8f); \
  ca.K = fmaf(p, __builtin_amdgcn_rcpf(den), ca.K); \
  float d2 = A.K - C.K; l2b.K = fmaf(d2, d2, l2b.K); \
  float p2 = A.K * C.K; \
  float dn2 = fmaxf(fabsf(A.K) * fabsf(C.K), 1e-8f); \
  cb.K = fmaf(p2, __builtin_amdgcn_rcpf(dn2), cb.K); }
  U1(x) U1(y) U1(z) U1(w)
#undef U1
}

__device__ __forceinline__ void upd2(const float4& S, const float4& T,
                                     float4& ssq, float4& ssm, float4& smx,
                                     float4& tsm, float4& tmx)
{
#define U2(K) { \
  float ds = S.K - T.K; ssq.K = fmaf(ds, ds, ssq.K); \
  ssm.K += S.K; tsm.K += T.K; \
  smx.K = fmaxf(smx.K, S.K); tmx.K = fmaxf(tmx.K, T.K); }
  U2(x) U2(y) U2(z) U2(w)
#undef U2
}

// ---------- Kernel BIG: A1 | A2 | KL by block range --------------------------
// A-phase: REGISTER-pipelined streaming (no LDS). There is zero data reuse in
// this phase, so LDS staging was a pure prefetch buffer that capped residency
// at 3 blocks/CU (48 KB). Plain float4 loads + depth-3 register double-buffer
// + full unroll lets the compiler track vmcnt per load; __launch_bounds(256,4)
// caps VGPR<=128 -> 16 waves/CU -> all 1024 blocks co-resident.
// blocks [0,256):    A1 (opt_t1/opt_t2/sar_t2 -> diff-map partials)
// blocks [256,512):  A2 (student/teacher stats + channel sums)
// blocks [512,1024): KL
__global__ __launch_bounds__(256, 4) void kernBIG(
    const float* __restrict__ o1p, const float* __restrict__ o2p,
    const float* __restrict__ srp,
    const float* __restrict__ stu, const float* __restrict__ tea,
    const float* __restrict__ so,  const float* __restrict__ to,
    float* __restrict__ ws)
{
  const int bid = blockIdx.x;
  const int tid = threadIdx.x, lane = tid & 63, w = tid >> 6;
  __shared__ float skl[8];

  if (bid < 256) {
    // ---------------- A1: diff maps ----------------
    const int b   = bid >> 5;          // image
    const int r   = bid & 31;
    const int wdw = r >> 3;            // 1024-px window
    const int cs  = r & 7;             // 32-channel slice
    const int c0  = cs * 32;
    const size_t base = ((size_t)(b * CCH + c0)) * HWPX + wdw * 1024 + tid * 4;
    const float* pA = o1p + base;
    const float* pB = o2p + base;
    const float* pC = srp + base;

    float4 l2a = {0,0,0,0}, ca = {0,0,0,0}, l2b = {0,0,0,0}, cb = {0,0,0,0};
    float4 Ab[3], Bb[3], Cb[3];
#pragma unroll
    for (int d = 0; d < 3; ++d) {
      Ab[d] = *(const float4*)(pA + (size_t)d * HWPX);
      Bb[d] = *(const float4*)(pB + (size_t)d * HWPX);
      Cb[d] = *(const float4*)(pC + (size_t)d * HWPX);
    }
#pragma unroll
    for (int s = 0; s < 32; ++s) {
      const int d = s % 3;             // compile-time under full unroll
      const float4 Av = Ab[d], Bv = Bb[d], Cv = Cb[d];
      if (s + 3 < 32) {
        Ab[d] = *(const float4*)(pA + (size_t)(s + 3) * HWPX);
        Bb[d] = *(const float4*)(pB + (size_t)(s + 3) * HWPX);
        Cb[d] = *(const float4*)(pC + (size_t)(s + 3) * HWPX);
      }
      upd1(Av, Bv, Cv, l2a, ca, l2b, cb);
    }

    const int gp4 = b * HWPX + wdw * 1024 + tid * 4;
    float* pa = ws + A1P_OFF;
    *(float4*)&pa[(0 * 8 + cs) * NPIX + gp4] = l2a;
    *(float4*)&pa[(1 * 8 + cs) * NPIX + gp4] = ca;
    *(float4*)&pa[(2 * 8 + cs) * NPIX + gp4] = l2b;
    *(float4*)&pa[(3 * 8 + cs) * NPIX + gp4] = cb;

  } else if (bid < 512) {
    // ---------------- A2: student/teacher stats + channel sums ----------------
    const int bidA = bid - 256;
    const int b   = bidA >> 5;
    const int r   = bidA & 31;
    const int wdw = r >> 3;
    const int cs  = r & 7;
    const int c0  = cs * 32;
    const size_t base = ((size_t)(b * CCH + c0)) * HWPX + wdw * 1024 + tid * 4;
    const float* pS = stu + base;
    const float* pT = tea + base;

    float4 ssq = {0,0,0,0}, ssm = {0,0,0,0}, tsm = {0,0,0,0};
    float4 smx = {-INFINITY,-INFINITY,-INFINITY,-INFINITY};
    float4 tmx = smx;
    float4 Sb[3], Tb[3];
#pragma unroll
    for (int d = 0; d < 3; ++d) {
      Sb[d] = *(const float4*)(pS + (size_t)d * HWPX);
      Tb[d] = *(const float4*)(pT + (size_t)d * HWPX);
    }
#pragma unroll
    for (int s = 0; s < 32; ++s) {
      const int d = s % 3;
      const float4 Sv = Sb[d], Tv = Tb[d];
      if (s + 3 < 32) {
        Sb[d] = *(const float4*)(pS + (size_t)(s + 3) * HWPX);
        Tb[d] = *(const float4*)(pT + (size_t)(s + 3) * HWPX);
      }
      upd2(Sv, Tv, ssq, ssm, smx, tsm, tmx);
      // per-(b,c) window sums (this channel)
      float csm = (Sv.x + Sv.y) + (Sv.z + Sv.w);
      float ctm = (Tv.x + Tv.y) + (Tv.z + Tv.w);
      csm = wred(csm); ctm = wred(ctm);
      if (lane == 0) {
        const int bc = b * CCH + c0 + s;
        ws[CHS_OFF + bc * 16 + wdw * 4 + w] = csm;
        ws[CHT_OFF + bc * 16 + wdw * 4 + w] = ctm;
      }
    }

    const int gp4 = b * HWPX + wdw * 1024 + tid * 4;
    float* pa = ws + A2P_OFF;
    *(float4*)&pa[(0 * 8 + cs) * NPIX + gp4] = ssq;
    *(float4*)&pa[(1 * 8 + cs) * NPIX + gp4] = ssm;
    *(float4*)&pa[(2 * 8 + cs) * NPIX + gp4] = smx;
    *(float4*)&pa[(3 * 8 + cs) * NPIX + gp4] = tsm;
    *(float4*)&pa[(4 * 8 + cs) * NPIX + gp4] = tmx;

  } else {
    // ---------------- KL: 2-way softmax KL + class1 MSE ----------------
    const int bkl = bid - 512;                 // 0..511
    const int gid = bkl * 256 + tid;
    const int p4 = gid << 2;
    const int b  = p4 >> 16;
    const int pp = p4 & 65535;
    const int i0 = b * 131072 + pp;

    const float4 s0 = *(const float4*)(so + i0);
    const float4 s1 = *(const float4*)(so + i0 + 65536);
    const float4 t0 = *(const float4*)(to + i0);
    const float4 t1 = *(const float4*)(to + i0 + 65536);

    float kl = 0.f, c1 = 0.f;
#define KLC(S0, S1, T0, T1)                                           \
    {                                                                 \
      float xs = (S1 - S0) * 0.25f;                                   \
      float xt = (T1 - T0) * 0.25f;                                   \
      float lzs = fmaxf(xs, 0.f) + log1pf(expf(-fabsf(xs)));          \
      float lzt = fmaxf(xt, 0.f) + log1pf(expf(-fabsf(xt)));          \
      float ls0 = -lzs, ls1 = xs - lzs;                               \
      float lt0 = -lzt, lt1 = xt - lzt;                               \
      float pt0 = expf(lt0), pt1 = expf(lt1);                         \
      kl += pt0 * (lt0 - ls0) + pt1 * (lt1 - ls1);                    \
      float ps1 = expf(ls1);                                          \
      float dd = ps1 - pt1;                                           \
      c1 += dd * dd;                                                  \
    }
    KLC(s0.x, s1.x, t0.x, t1.x)
    KLC(s0.y, s1.y, t0.y, t1.y)
    KLC(s0.z, s1.z, t0.z, t1.z)
    KLC(s0.w, s1.w, t0.w, t1.w)
#undef KLC

    kl = wred(kl);
    c1 = wred(c1);
    if ((tid & 63) == 0) { skl[w * 2] = kl; skl[w * 2 + 1] = c1; }
    __syncthreads();
    if (tid == 0) {
      ws[KLP_OFF + bkl] = skl[0] + skl[2] + skl[4] + skl[6];
      ws[CL1_OFF + bkl] = skl[1] + skl[3] + skl[5] + skl[7];
    }
  }
}

// ---------- Kernel C1: cross-slice combine, finalize maps, phase-1 sums ------
__global__ __launch_bounds__(256) void kernC1(
    const float* __restrict__ mk, float* __restrict__ ws)
{
  const int tid = threadIdx.x;
  const int gp = blockIdx.x * 256 + tid;
  if (blockIdx.x == 0 && tid == 0) *(unsigned*)(ws + CNT_OFF) = 0u;  // arm C2D counter
  const float* pA = ws + A1P_OFF;
  const float* pB = ws + A2P_OFF;

  float a0 = 0.f, a1 = 0.f, a2 = 0.f, a3 = 0.f;
  float b0 = 0.f, b1 = 0.f, b3 = 0.f;
  float m2 = -INFINITY, m4 = -INFINITY;
#pragma unroll
  for (int s = 0; s < 8; ++s) {
    a0 += pA[(0 * 8 + s) * NPIX + gp];
    a1 += pA[(1 * 8 + s) * NPIX + gp];
    a2 += pA[(2 * 8 + s) * NPIX + gp];
    a3 += pA[(3 * 8 + s) * NPIX + gp];
    b0 += pB[(0 * 8 + s) * NPIX + gp];
    b1 += pB[(1 * 8 + s) * NPIX + gp];
    m2 = fmaxf(m2, pB[(2 * 8 + s) * NPIX + gp]);
    b3 += pB[(3 * 8 + s) * NPIX + gp];
    m4 = fmaxf(m4, pB[(4 * 8 + s) * NPIX + gp]);
  }

  const float l2o = sqrtf(a0 + 1e-6f);
  const float opt_d = (l2o + 1.0f - a1 * (1.0f / 256.0f)) * sigmoidf_(l2o * 5.0f);
  const float l2h = sqrtf(a2 + 1e-6f);
  const float het_d = (l2h + 1.0f - a3 * (1.0f / 256.0f)) * sigmoidf_(l2h * 5.0f);
  const float ssp = sigmoidf_(b1 * (1.0f / 256.0f) + m2);
  const float tsp = sigmoidf_(b3 * (1.0f / 256.0f) + m4);

  ws[OPTD_OFF + gp] = opt_d;
  ws[HETD_OFF + gp] = het_d;
  ws[SSP_OFF  + gp] = ssp;
  ws[TSP_OFF  + gp] = tsp;

  const float mv = mk[gp];
  float r0 = b0, r1 = mv * mv * b0, r2 = opt_d;
  r0 = wred(r0); r1 = wred(r1); r2 = wred(r2);
  __shared__ float red[4][3];
  const int w = tid >> 6;
  if ((tid & 63) == 0) { red[w][0] = r0; red[w][1] = r1; red[w][2] = r2; }
  __syncthreads();
  if (tid == 0) {
    ws[GP0_OFF + blockIdx.x] = red[0][0] + red[1][0] + red[2][0] + red[3][0];
    ws[GP1_OFF + blockIdx.x] = red[0][1] + red[1][1] + red[2][1] + red[3][1];
    ws[GP2_OFF + blockIdx.x] = red[0][2] + red[1][2] + red[2][2] + red[3][2];
  }
}

// ---------- Kernel C2D: mean-dependent terms + final combine (last block) ----
__global__ __launch_bounds__(256) void kernC2D(float* __restrict__ ws,
                                               float* __restrict__ out)
{
  const int tid = threadIdx.x;
  const int gid = blockIdx.x * 256 + tid;

  // re-derive sum(opt_diff) from the 128 C1 partials
  float v = (tid < 128) ? ws[GP2_OFF + tid] : 0.f;
  v = wred(v);
  __shared__ float smo[4];
  if ((tid & 63) == 0) smo[tid >> 6] = v;
  __syncthreads();
  const float mean_opt = (smo[0] + smo[1] + smo[2] + smo[3]) * (1.0f / 32768.0f);
  const float att_w = sigmoidf_(mean_opt * 10.0f);
  const float thr = mean_opt * 1.5f;

  const float od  = ws[OPTD_OFF + gid];
  const float hd  = ws[HETD_OFF + gid];
  const float ssp = ws[SSP_OFF + gid];
  const float tsp = ws[TSP_OFF + gid];
  const float mask = od > thr ? 1.0f : 0.0f;
  const float wgt = mask * 2.0f + (1.0f - mask) * 0.5f;
  float dt = (hd - od) * wgt; dt *= dt;
  const float amp = 1.0f + att_w * mask;
  float st = (ssp - tsp) * amp; st *= st;

  float cf = 0.f, catt = 0.f;
  if (gid < NCHAN) {
    float s = 0.f, t = 0.f;
#pragma unroll
    for (int k = 0; k < 16; ++k) {
      s += ws[CHS_OFF + gid * 16 + k];
      t += ws[CHT_OFF + gid * 16 + k];
    }
    const float smn = s * (1.0f / 4096.0f);
    const float tmn = t * (1.0f / 4096.0f);
    const float d = smn - tmn;
    cf = d * d;
    const float d2 = sigmoidf_(smn) - sigmoidf_(tmn);
    catt = d2 * d2;
  }

  dt = wred(dt); st = wred(st); cf = wred(cf); catt = wred(catt);
  __shared__ float red[4][4];
  const int w = tid >> 6;
  if ((tid & 63) == 0) { red[w][0] = dt; red[w][1] = st; red[w][2] = cf; red[w][3] = catt; }
  __syncthreads();
  if (tid == 0) {
    __hip_atomic_store(ws + DTP_OFF + blockIdx.x,
                       red[0][0] + red[1][0] + red[2][0] + red[3][0],
                       __ATOMIC_RELAXED, __HIP_MEMORY_SCOPE_AGENT);
    __hip_atomic_store(ws + STP_OFF + blockIdx.x,
                       red[0][1] + red[1][1] + red[2][1] + red[3][1],
                       __ATOMIC_RELAXED, __HIP_MEMORY_SCOPE_AGENT);
    __hip_atomic_store(ws + CFP_OFF + blockIdx.x,
                       red[0][2] + red[1][2] + red[2][2] + red[3][2],
                       __ATOMIC_RELAXED, __HIP_MEMORY_SCOPE_AGENT);
    __hip_atomic_store(ws + CAP_OFF + blockIdx.x,
                       red[0][3] + red[1][3] + red[2][3] + red[3][3],
                       __ATOMIC_RELAXED, __HIP_MEMORY_SCOPE_AGENT);
  }

  // ---- last block performs the final combine ----
  __shared__ bool isLast;
  if (tid == 0) {
    __threadfence();
    unsigned prev = __hip_atomic_fetch_add((unsigned*)(ws + CNT_OFF), 1u,
                                           __ATOMIC_ACQ_REL, __HIP_MEMORY_SCOPE_AGENT);
    isLast = (prev == 127u);
  }
  __syncthreads();
  if (!isLast) return;
  __threadfence();

  __shared__ float sm[4];
  auto bsum = [&](int off, int n) -> float {
    float acc = 0.f;
    for (int i = tid; i < n; i += 256)
      acc += __hip_atomic_load(ws + off + i, __ATOMIC_RELAXED, __HIP_MEMORY_SCOPE_AGENT);
    acc = wred(acc);
    if ((tid & 63) == 0) sm[tid >> 6] = acc;
    __syncthreads();
    const float r = sm[0] + sm[1] + sm[2] + sm[3];
    __syncthreads();
    return r;
  };

  const float ssqg = bsum(GP0_OFF, 128);
  const float ssql = bsum(GP1_OFF, 128);
  const float sopt = bsum(GP2_OFF, 128);
  const float kls  = bsum(KLP_OFF, 512);
  const float c1s  = bsum(CL1_OFF, 512);
  const float dts  = bsum(DTP_OFF, 128);
  const float sts  = bsum(STP_OFF, 128);
  const float cfs  = bsum(CFP_OFF, 128);
  const float cas  = bsum(CAP_OFF, 128);

  if (tid == 0) {
    const float global_loss = ssqg * (1.0f / (float)NFEAT);
    const float local_loss  = ssql * (1.0f / (float)NFEAT);
    const float chan_f      = cfs * (1.0f / (float)NCHAN);
    const float feat = 0.3f * global_loss + 0.5f * local_loss + 0.2f * chan_f;

    const float kl = kls * 2.0f;                 // * T^2 / B = 16/8
    const float c1 = c1s * (2.0f / 524288.0f);
    const float outl = kl + c1;

    const float mo = sopt * (1.0f / 32768.0f);
    const float aw = sigmoidf_(mo * 10.0f);
    const float diff_loss = dts * (1.0f / 32768.0f);
    const float spat_loss = sts * (1.0f / 32768.0f);
    const float chan_att  = cas * (1.0f / (float)NCHAN);

    const float alpha = 0.5f * (1.0f + 0.5f * aw);
    const float beta  = 0.3f * (1.0f - 0.3f * aw);
    const float gamma = 0.2f * (1.0f + 0.5f * aw);
    const float datt = alpha * diff_loss + beta * chan_att + gamma * spat_loss;

    const float total = 0.3f * feat + 0.4f * outl + 0.3f * datt;
    out[0] = total;
    out[1] = feat;
    out[2] = outl;
    out[3] = datt;
  }
}

extern "C" void kernel_launch(void* const* d_in, const int* in_sizes, int n_in,
                              void* d_out, int out_size, void* d_ws, size_t ws_size,
                              hipStream_t stream)
{
  const float* stu = (const float*)d_in[0];
  const float* tea = (const float*)d_in[1];
  const float* so  = (const float*)d_in[2];
  const float* to  = (const float*)d_in[3];
  const float* o1  = (const float*)d_in[4];
  const float* o2  = (const float*)d_in[5];
  const float* sr  = (const float*)d_in[6];
  const float* mk  = (const float*)d_in[7];
  float* ws  = (float*)d_ws;
  float* out = (float*)d_out;

  kernBIG<<<1024, 256, 0, stream>>>(o1, o2, sr, stu, tea, so, to, ws);
  kernC1<<<128, 256, 0, stream>>>(mk, ws);
  kernC2D<<<128, 256, 0, stream>>>(ws, out);
}

// Round 3
// 205.792 us; speedup vs baseline: 1.4197x; 1.2190x over previous
//
#include <hip/hip_runtime.h>
#include <math.h>

// Geometry: features [B=8,C=256,H=64,W=64]; outputs [8,2,256,256]
#define HWPX  4096
#define CCH   256
#define NPIX  32768
#define NCHAN 2048
#define NFEAT 8388608

// Workspace layout (floats). Every cell written before read; counters armed
// inside kernBIG (block 512), read only by kernC (next dispatch).
#define A1P_OFF   0                         // 4q x 8slices x NPIX (A1 partials)
#define A2P_OFF   (A1P_OFF + 4*8*NPIX)      // 4q x 8slices x NPIX (A2 partials)
#define CHS_OFF   (A2P_OFF + 4*8*NPIX)      // 2048 bc x 16 slots (4 wdw x 4 waves)
#define CHT_OFF   (CHS_OFF + NCHAN*16)
#define KLP_OFF   (CHT_OFF + NCHAN*16)      // 512 block partials (KL)
#define CL1_OFF   (KLP_OFF + 512)
#define GQ0_OFF   (CL1_OFF + 512)           // 256 (A2 block sums: global)
#define GQ1_OFF   (GQ0_OFF + 256)           // 256 (A2 block sums: local/masked)
#define GP2_OFF   (GQ1_OFF + 256)           // 128 (kernC slice sums of opt_d)
#define DTP_OFF   (GP2_OFF + 128)           // 128 (kernC phase-2 partials)
#define STP_OFF   (DTP_OFF + 128)
#define CFP_OFF   (STP_OFF + 128)
#define CAP_OFF   (CFP_OFF + 128)
#define CNT_OFF   (CAP_OFF + 128)           // 2 counters (armed by kernBIG b512)

// s_waitcnt with vmcnt(N), lgkm/exp unconstrained (gfx9 encoding)
#define WAITVM(N) __builtin_amdgcn_s_waitcnt(0xF70 | (N))

__device__ __forceinline__ void async16(const float* g, float* l) {
  __builtin_amdgcn_global_load_lds(
      (const __attribute__((address_space(1))) void*)g,
      (__attribute__((address_space(3))) void*)l, 16, 0, 0);
}

__device__ __forceinline__ float sigmoidf_(float x) { return 1.0f / (1.0f + expf(-x)); }

__device__ __forceinline__ float wred(float v) {
#pragma unroll
  for (int o = 32; o > 0; o >>= 1) v += __shfl_down(v, o, 64);
  return v;
}

__device__ __forceinline__ void upd1(const float4& A, const float4& B, const float4& C,
                                     float4& l2a, float4& ca, float4& l2b, float4& cb)
{
#define U1(K) { \
  float d = A.K - B.K; l2a.K = fmaf(d, d, l2a.K); \
  float p = A.K * B.K; \
  float den = fmaxf(fabsf(A.K) * fabsf(B.K), 1e-8f); \
  ca.K = fmaf(p, __builtin_amdgcn_rcpf(den), ca.K); \
  float d2 = A.K - C.K; l2b.K = fmaf(d2, d2, l2b.K); \
  float p2 = A.K * C.K; \
  float dn2 = fmaxf(fabsf(A.K) * fabsf(C.K), 1e-8f); \
  cb.K = fmaf(p2, __builtin_amdgcn_rcpf(dn2), cb.K); }
  U1(x) U1(y) U1(z) U1(w)
#undef U1
}

__device__ __forceinline__ void upd2(const float4& S, const float4& T,
                                     float4& ssq, float4& ssm, float4& smx,
                                     float4& tsm, float4& tmx)
{
#define U2(K) { \
  float ds = S.K - T.K; ssq.K = fmaf(ds, ds, ssq.K); \
  ssm.K += S.K; tsm.K += T.K; \
  smx.K = fmaxf(smx.K, S.K); tmx.K = fmaxf(tmx.K, T.K); }
  U2(x) U2(y) U2(z) U2(w)
#undef U2
}

// ---------- Kernel BIG: A1 | A2 | KL by block range --------------------------
// A-phase: global_load_lds staging (LOAD-BEARING for LLC residency -- R2 showed
// plain vector loads blow FETCH 24->137 MB). Depth-3 per-wave async pipeline
// (9KB in flight/wave for A1), 36 KB LDS -> 4 blocks/CU. Each wave stages and
// consumes ONLY its own 1KB LDS slice -> zero barriers in the K-loop.
// blocks [0,256):    A1 (opt_t1/opt_t2/sar_t2 -> diff-map partials)
// blocks [256,512):  A2 (student/teacher stats + channel sums + ssq block-sums)
// blocks [512,1024): KL  (block 512 also arms the kernC counters)
__global__ __launch_bounds__(256) void kernBIG(
    const float* __restrict__ o1p, const float* __restrict__ o2p,
    const float* __restrict__ srp,
    const float* __restrict__ stu, const float* __restrict__ tea,
    const float* __restrict__ so,  const float* __restrict__ to,
    const float* __restrict__ mk,
    float* __restrict__ ws)
{
  const int bid = blockIdx.x;
  const int tid = threadIdx.x, lane = tid & 63, w = tid >> 6;
  __shared__ float sb[3][3][1024];   // 36 KB staging (A1: 3 streams; A2: 2)
  __shared__ float gred[4][2];

  if (bid < 256) {
    // ---------------- A1: diff maps ----------------
    const int b   = bid >> 5;          // image
    const int r   = bid & 31;
    const int wdw = r >> 3;            // 1024-px window
    const int cs  = r & 7;             // 32-channel slice
    const int c0  = cs * 32;
    const size_t base = ((size_t)(b * CCH + c0)) * HWPX + wdw * 1024 + lane * 4;
    const int wo = w * 256;            // this wave's LDS slice

#define STAGE1(d, step) { \
    const size_t o = base + (size_t)(step) * HWPX; \
    async16(o1p + o, &sb[d][0][wo]); \
    async16(o2p + o, &sb[d][1][wo]); \
    async16(srp + o, &sb[d][2][wo]); }

    STAGE1(0, 0) STAGE1(1, 1) STAGE1(2, 2)

    float4 l2a = {0,0,0,0}, ca = {0,0,0,0}, l2b = {0,0,0,0}, cb = {0,0,0,0};
    int d = 0;
    for (int s = 0; s < 32; ++s) {
      if (s <= 29)      WAITVM(6);     // wait step s's 3 loads (<=9 outstanding)
      else if (s == 30) WAITVM(3);
      else              WAITVM(0);
      __builtin_amdgcn_sched_barrier(0);
      const float4 Av = *(const float4*)&sb[d][0][tid * 4];
      const float4 Bv = *(const float4*)&sb[d][1][tid * 4];
      const float4 Cv = *(const float4*)&sb[d][2][tid * 4];
      upd1(Av, Bv, Cv, l2a, ca, l2b, cb);
      if (s + 3 < 32) STAGE1(d, s + 3);
      d = (d == 2) ? 0 : d + 1;
    }
#undef STAGE1

    const int gp4 = b * HWPX + wdw * 1024 + tid * 4;
    float* pa = ws + A1P_OFF;
    *(float4*)&pa[(0 * 8 + cs) * NPIX + gp4] = l2a;
    *(float4*)&pa[(1 * 8 + cs) * NPIX + gp4] = ca;
    *(float4*)&pa[(2 * 8 + cs) * NPIX + gp4] = l2b;
    *(float4*)&pa[(3 * 8 + cs) * NPIX + gp4] = cb;

  } else if (bid < 512) {
    // ---------------- A2: student/teacher stats + channel sums ----------------
    const int bidA = bid - 256;
    const int b   = bidA >> 5;
    const int r   = bidA & 31;
    const int wdw = r >> 3;
    const int cs  = r & 7;
    const int c0  = cs * 32;
    const size_t base = ((size_t)(b * CCH + c0)) * HWPX + wdw * 1024 + lane * 4;
    const int wo = w * 256;

#define STAGE2(d, step) { \
    const size_t o = base + (size_t)(step) * HWPX; \
    async16(stu + o, &sb[d][0][wo]); \
    async16(tea + o, &sb[d][1][wo]); }

    STAGE2(0, 0) STAGE2(1, 1) STAGE2(2, 2)

    float4 ssq = {0,0,0,0}, ssm = {0,0,0,0}, tsm = {0,0,0,0};
    float4 smx = {-INFINITY,-INFINITY,-INFINITY,-INFINITY};
    float4 tmx = smx;
    int d = 0;
    for (int s = 0; s < 32; ++s) {
      if (s <= 29)      WAITVM(4);     // wait step s's 2 loads (<=6 outstanding)
      else if (s == 30) WAITVM(2);
      else              WAITVM(0);
      __builtin_amdgcn_sched_barrier(0);
      const float4 Sv = *(const float4*)&sb[d][0][tid * 4];
      const float4 Tv = *(const float4*)&sb[d][1][tid * 4];
      upd2(Sv, Tv, ssq, ssm, smx, tsm, tmx);
      // per-(b,c) window sums (this channel)
      float csm = (Sv.x + Sv.y) + (Sv.z + Sv.w);
      float ctm = (Tv.x + Tv.y) + (Tv.z + Tv.w);
      csm = wred(csm); ctm = wred(ctm);
      if (lane == 0) {
        const int bc = b * CCH + c0 + s;
        ws[CHS_OFF + bc * 16 + wdw * 4 + w] = csm;
        ws[CHT_OFF + bc * 16 + wdw * 4 + w] = ctm;
      }
      if (s + 3 < 32) STAGE2(d, s + 3);
      d = (d == 2) ? 0 : d + 1;
    }
#undef STAGE2

    const int gp4 = b * HWPX + wdw * 1024 + tid * 4;
    float* pa = ws + A2P_OFF;
    *(float4*)&pa[(0 * 8 + cs) * NPIX + gp4] = ssm;
    *(float4*)&pa[(1 * 8 + cs) * NPIX + gp4] = smx;
    *(float4*)&pa[(2 * 8 + cs) * NPIX + gp4] = tsm;
    *(float4*)&pa[(3 * 8 + cs) * NPIX + gp4] = tmx;

    // ssq folded to block scalars: global (plain) + local (mask^2-weighted).
    const float4 mv4 = *(const float4*)(mk + b * HWPX + wdw * 1024 + tid * 4);
    float g0 = (ssq.x + ssq.y) + (ssq.z + ssq.w);
    float g1 = mv4.x * mv4.x * ssq.x + mv4.y * mv4.y * ssq.y
             + mv4.z * mv4.z * ssq.z + mv4.w * mv4.w * ssq.w;
    g0 = wred(g0); g1 = wred(g1);
    if (lane == 0) { gred[w][0] = g0; gred[w][1] = g1; }
    __syncthreads();
    if (tid == 0) {
      ws[GQ0_OFF + bidA] = gred[0][0] + gred[1][0] + gred[2][0] + gred[3][0];
      ws[GQ1_OFF + bidA] = gred[0][1] + gred[1][1] + gred[2][1] + gred[3][1];
    }

  } else {
    // ---------------- KL: 2-way softmax KL + class1 MSE ----------------
    const int bkl = bid - 512;                 // 0..511
    if (bkl == 0 && tid == 0) {                // arm kernC's two counters
      ((unsigned*)(ws + CNT_OFF))[0] = 0u;
      ((unsigned*)(ws + CNT_OFF))[1] = 0u;
    }
    const int gid = bkl * 256 + tid;
    const int p4 = gid << 2;
    const int b  = p4 >> 16;
    const int pp = p4 & 65535;
    const int i0 = b * 131072 + pp;

    const float4 s0 = *(const float4*)(so + i0);
    const float4 s1 = *(const float4*)(so + i0 + 65536);
    const float4 t0 = *(const float4*)(to + i0);
    const float4 t1 = *(const float4*)(to + i0 + 65536);

    float kl = 0.f, c1 = 0.f;
#define KLC(S0, S1, T0, T1)                                           \
    {                                                                 \
      float xs = (S1 - S0) * 0.25f;                                   \
      float xt = (T1 - T0) * 0.25f;                                   \
      float lzs = fmaxf(xs, 0.f) + log1pf(expf(-fabsf(xs)));          \
      float lzt = fmaxf(xt, 0.f) + log1pf(expf(-fabsf(xt)));          \
      float ls0 = -lzs, ls1 = xs - lzs;                               \
      float lt0 = -lzt, lt1 = xt - lzt;                               \
      float pt0 = expf(lt0), pt1 = expf(lt1);                         \
      kl += pt0 * (lt0 - ls0) + pt1 * (lt1 - ls1);                    \
      float ps1 = expf(ls1);                                          \
      float dd = ps1 - pt1;                                           \
      c1 += dd * dd;                                                  \
    }
    KLC(s0.x, s1.x, t0.x, t1.x)
    KLC(s0.y, s1.y, t0.y, t1.y)
    KLC(s0.z, s1.z, t0.z, t1.z)
    KLC(s0.w, s1.w, t0.w, t1.w)
#undef KLC

    kl = wred(kl);
    c1 = wred(c1);
    if ((tid & 63) == 0) { gred[w][0] = kl; gred[w][1] = c1; }
    __syncthreads();
    if (tid == 0) {
      ws[KLP_OFF + bkl] = gred[0][0] + gred[1][0] + gred[2][0] + gred[3][0];
      ws[CL1_OFF + bkl] = gred[0][1] + gred[1][1] + gred[2][1] + gred[3][1];
    }
  }
}

// ---------- Kernel C: combine + maps-in-registers + two-level ticket ---------
// 128 blocks (all trivially co-resident on 256 CUs -> spin is deadlock-safe).
// Level 1: all blocks publish GP2 (slice sum of opt_d), spin to 128, then all
// compute mean-dependent terms with od/hd/ssp/tsp still in registers.
// Level 2: publish phase-2 partials; last block (prev==127) does final combine.
__global__ __launch_bounds__(256) void kernC(float* __restrict__ ws,
                                             float* __restrict__ out)
{
  const int tid = threadIdx.x, w = tid >> 6;
  const int slice = blockIdx.x;
  const int gp = slice * 256 + tid;
  unsigned* cnt0 = (unsigned*)(ws + CNT_OFF);
  unsigned* cnt1 = cnt0 + 1;
  __shared__ float red[4][4];
  __shared__ float sm[4];
  __shared__ bool isLast;

  // ---- C1 part: cross-slice combine (maps stay in registers) ----
  const float* pA = ws + A1P_OFF;
  const float* pB = ws + A2P_OFF;
  float a0 = 0.f, a1 = 0.f, a2 = 0.f, a3 = 0.f;
  float b1 = 0.f, b3 = 0.f;
  float m2 = -INFINITY, m4 = -INFINITY;
#pragma unroll
  for (int s = 0; s < 8; ++s) {
    a0 += pA[(0 * 8 + s) * NPIX + gp];
    a1 += pA[(1 * 8 + s) * NPIX + gp];
    a2 += pA[(2 * 8 + s) * NPIX + gp];
    a3 += pA[(3 * 8 + s) * NPIX + gp];
    b1 += pB[(0 * 8 + s) * NPIX + gp];
    m2 = fmaxf(m2, pB[(1 * 8 + s) * NPIX + gp]);
    b3 += pB[(2 * 8 + s) * NPIX + gp];
    m4 = fmaxf(m4, pB[(3 * 8 + s) * NPIX + gp]);
  }

  const float l2o = sqrtf(a0 + 1e-6f);
  const float od  = (l2o + 1.0f - a1 * (1.0f / 256.0f)) * sigmoidf_(l2o * 5.0f);
  const float l2h = sqrtf(a2 + 1e-6f);
  const float hd  = (l2h + 1.0f - a3 * (1.0f / 256.0f)) * sigmoidf_(l2h * 5.0f);
  const float ssp = sigmoidf_(b1 * (1.0f / 256.0f) + m2);
  const float tsp = sigmoidf_(b3 * (1.0f / 256.0f) + m4);

  float r2 = wred(od);
  if ((tid & 63) == 0) red[w][0] = r2;
  __syncthreads();
  if (tid == 0) {
    __hip_atomic_store(ws + GP2_OFF + slice,
                       red[0][0] + red[1][0] + red[2][0] + red[3][0],
                       __ATOMIC_RELAXED, __HIP_MEMORY_SCOPE_AGENT);
    __threadfence();
    __hip_atomic_fetch_add(cnt0, 1u, __ATOMIC_ACQ_REL, __HIP_MEMORY_SCOPE_AGENT);
    while (__hip_atomic_load(cnt0, __ATOMIC_RELAXED,
                             __HIP_MEMORY_SCOPE_AGENT) < 128u)
      __builtin_amdgcn_s_sleep(1);
  }
  __syncthreads();
  __threadfence();

  // ---- C2D part: mean-dependent terms ----
  float v = (tid < 128)
      ? __hip_atomic_load(ws + GP2_OFF + tid, __ATOMIC_RELAXED,
                          __HIP_MEMORY_SCOPE_AGENT)
      : 0.f;
  v = wred(v);
  if ((tid & 63) == 0) sm[w] = v;
  __syncthreads();
  const float mean_opt = (sm[0] + sm[1] + sm[2] + sm[3]) * (1.0f / 32768.0f);
  const float att_w = sigmoidf_(mean_opt * 10.0f);
  const float thr = mean_opt * 1.5f;

  const float mask = od > thr ? 1.0f : 0.0f;
  const float wgt = mask * 2.0f + (1.0f - mask) * 0.5f;
  float dt = (hd - od) * wgt; dt *= dt;
  const float amp = 1.0f + att_w * mask;
  float st = (ssp - tsp) * amp; st *= st;

  float cf = 0.f, catt = 0.f;
  if (gp < NCHAN) {
    float s = 0.f, t = 0.f;
#pragma unroll
    for (int k = 0; k < 16; ++k) {
      s += ws[CHS_OFF + gp * 16 + k];
      t += ws[CHT_OFF + gp * 16 + k];
    }
    const float smn = s * (1.0f / 4096.0f);
    const float tmn = t * (1.0f / 4096.0f);
    const float dch = smn - tmn;
    cf = dch * dch;
    const float d2 = sigmoidf_(smn) - sigmoidf_(tmn);
    catt = d2 * d2;
  }

  dt = wred(dt); st = wred(st); cf = wred(cf); catt = wred(catt);
  __syncthreads();                           // red[] reuse
  if ((tid & 63) == 0) { red[w][0] = dt; red[w][1] = st; red[w][2] = cf; red[w][3] = catt; }
  __syncthreads();
  if (tid == 0) {
    __hip_atomic_store(ws + DTP_OFF + slice,
                       red[0][0] + red[1][0] + red[2][0] + red[3][0],
                       __ATOMIC_RELAXED, __HIP_MEMORY_SCOPE_AGENT);
    __hip_atomic_store(ws + STP_OFF + slice,
                       red[0][1] + red[1][1] + red[2][1] + red[3][1],
                       __ATOMIC_RELAXED, __HIP_MEMORY_SCOPE_AGENT);
    __hip_atomic_store(ws + CFP_OFF + slice,
                       red[0][2] + red[1][2] + red[2][2] + red[3][2],
                       __ATOMIC_RELAXED, __HIP_MEMORY_SCOPE_AGENT);
    __hip_atomic_store(ws + CAP_OFF + slice,
                       red[0][3] + red[1][3] + red[2][3] + red[3][3],
                       __ATOMIC_RELAXED, __HIP_MEMORY_SCOPE_AGENT);
    __threadfence();
    unsigned prev = __hip_atomic_fetch_add(cnt1, 1u, __ATOMIC_ACQ_REL,
                                           __HIP_MEMORY_SCOPE_AGENT);
    isLast = (prev == 127u);
  }
  __syncthreads();
  if (!isLast) return;
  __threadfence();

  // ---- last block performs the final combine ----
  auto bsum = [&](int off, int n) -> float {
    float acc = 0.f;
    for (int i = tid; i < n; i += 256)
      acc += __hip_atomic_load(ws + off + i, __ATOMIC_RELAXED, __HIP_MEMORY_SCOPE_AGENT);
    acc = wred(acc);
    if ((tid & 63) == 0) sm[tid >> 6] = acc;
    __syncthreads();
    const float r = sm[0] + sm[1] + sm[2] + sm[3];
    __syncthreads();
    return r;
  };

  const float ssqg = bsum(GQ0_OFF, 256);
  const float ssql = bsum(GQ1_OFF, 256);
  const float sopt = bsum(GP2_OFF, 128);
  const float kls  = bsum(KLP_OFF, 512);
  const float c1s  = bsum(CL1_OFF, 512);
  const float dts  = bsum(DTP_OFF, 128);
  const float sts  = bsum(STP_OFF, 128);
  const float cfs  = bsum(CFP_OFF, 128);
  const float cas  = bsum(CAP_OFF, 128);

  if (tid == 0) {
    const float global_loss = ssqg * (1.0f / (float)NFEAT);
    const float local_loss  = ssql * (1.0f / (float)NFEAT);
    const float chan_f      = cfs * (1.0f / (float)NCHAN);
    const float feat = 0.3f * global_loss + 0.5f * local_loss + 0.2f * chan_f;

    const float kl = kls * 2.0f;                 // * T^2 / B = 16/8
    const float c1 = c1s * (2.0f / 524288.0f);
    const float outl = kl + c1;

    const float mo = sopt * (1.0f / 32768.0f);
    const float aw = sigmoidf_(mo * 10.0f);
    const float diff_loss = dts * (1.0f / 32768.0f);
    const float spat_loss = sts * (1.0f / 32768.0f);
    const float chan_att  = cas * (1.0f / (float)NCHAN);

    const float alpha = 0.5f * (1.0f + 0.5f * aw);
    const float beta  = 0.3f * (1.0f - 0.3f * aw);
    const float gamma = 0.2f * (1.0f + 0.5f * aw);
    const float datt = alpha * diff_loss + beta * chan_att + gamma * spat_loss;

    const float total = 0.3f * feat + 0.4f * outl + 0.3f * datt;
    out[0] = total;
    out[1] = feat;
    out[2] = outl;
    out[3] = datt;
  }
}

extern "C" void kernel_launch(void* const* d_in, const int* in_sizes, int n_in,
                              void* d_out, int out_size, void* d_ws, size_t ws_size,
                              hipStream_t stream)
{
  const float* stu = (const float*)d_in[0];
  const float* tea = (const float*)d_in[1];
  const float* so  = (const float*)d_in[2];
  const float* to  = (const float*)d_in[3];
  const float* o1  = (const float*)d_in[4];
  const float* o2  = (const float*)d_in[5];
  const float* sr  = (const float*)d_in[6];
  const float* mk  = (const float*)d_in[7];
  float* ws  = (float*)d_ws;
  float* out = (float*)d_out;

  kernBIG<<<1024, 256, 0, stream>>>(o1, o2, sr, stu, tea, so, to, mk, ws);
  kernC<<<128, 256, 0, stream>>>(ws, out);
}

// Round 4
// 204.063 us; speedup vs baseline: 1.4317x; 1.0085x over previous
//
#include <hip/hip_runtime.h>
#include <math.h>

// Geometry: features [B=8,C=256,H=64,W=64]; outputs [8,2,256,256]
#define HWPX  4096
#define CCH   256
#define NPIX  32768
#define NCHAN 2048
#define NFEAT 8388608

// Workspace layout (floats). Every cell written before read; counters armed
// inside kernBIG (first KL block), read only by kernC (next dispatch).
#define A1P_OFF   0                         // 4q x 8slices x NPIX (A1 partials)
#define A2P_OFF   (A1P_OFF + 4*8*NPIX)      // 4q x 8slices x NPIX (A2 partials)
#define CHS_OFF   (A2P_OFF + 4*8*NPIX)      // 2048 bc x 16 slots (8 wdw x 2 waves)
#define CHT_OFF   (CHS_OFF + NCHAN*16)
#define KLP_OFF   (CHT_OFF + NCHAN*16)      // 1024 block partials (KL)
#define CL1_OFF   (KLP_OFF + 1024)
#define GQ0_OFF   (CL1_OFF + 1024)          // 512 (A2 block sums: global ssq)
#define GQ1_OFF   (GQ0_OFF + 512)           // 512 (A2 block sums: masked ssq)
#define GP2_OFF   (GQ1_OFF + 512)           // 128 (kernC slice sums of opt_d)
#define DTP_OFF   (GP2_OFF + 128)           // 128 (kernC phase-2 partials)
#define STP_OFF   (DTP_OFF + 128)
#define CFP_OFF   (STP_OFF + 128)
#define CAP_OFF   (CFP_OFF + 128)
#define CNT_OFF   (CAP_OFF + 128)           // 2 counters (armed by kernBIG)

// s_waitcnt with vmcnt(N), lgkm/exp unconstrained (gfx9 encoding)
#define WAITVM(N) __builtin_amdgcn_s_waitcnt(0xF70 | (N))

__device__ __forceinline__ void async16(const float* g, float* l) {
  __builtin_amdgcn_global_load_lds(
      (const __attribute__((address_space(1))) void*)g,
      (__attribute__((address_space(3))) void*)l, 16, 0, 0);
}

__device__ __forceinline__ float sigmoidf_(float x) { return 1.0f / (1.0f + expf(-x)); }

__device__ __forceinline__ float wred(float v) {
#pragma unroll
  for (int o = 32; o > 0; o >>= 1) v += __shfl_down(v, o, 64);
  return v;
}

__device__ __forceinline__ void upd1(const float4& A, const float4& B, const float4& C,
                                     float4& l2a, float4& ca, float4& l2b, float4& cb)
{
#define U1(K) { \
  float d = A.K - B.K; l2a.K = fmaf(d, d, l2a.K); \
  float p = A.K * B.K; \
  float den = fmaxf(fabsf(A.K) * fabsf(B.K), 1e-8f); \
  ca.K = fmaf(p, __builtin_amdgcn_rcpf(den), ca.K); \
  float d2 = A.K - C.K; l2b.K = fmaf(d2, d2, l2b.K); \
  float p2 = A.K * C.K; \
  float dn2 = fmaxf(fabsf(A.K) * fabsf(C.K), 1e-8f); \
  cb.K = fmaf(p2, __builtin_amdgcn_rcpf(dn2), cb.K); }
  U1(x) U1(y) U1(z) U1(w)
#undef U1
}

__device__ __forceinline__ void upd2(const float4& S, const float4& T,
                                     float4& ssq, float4& ssm, float4& smx,
                                     float4& tsm, float4& tmx)
{
#define U2(K) { \
  float ds = S.K - T.K; ssq.K = fmaf(ds, ds, ssq.K); \
  ssm.K += S.K; tsm.K += T.K; \
  smx.K = fmaxf(smx.K, S.K); tmx.K = fmaxf(tmx.K, T.K); }
  U2(x) U2(y) U2(z) U2(w)
#undef U2
}

// ---------- Kernel BIG: A1 | A2 | KL by block range --------------------------
// 128-thread blocks (2 waves), 512-px windows. A-blocks first (1024 of them),
// KL blocks LAST (1024): with 18 KB LDS -> 8 blocks/CU -> 2048 resident slots,
// so the ENTIRE A phase runs with 8 A-blocks/CU (16 waves, ~120 KB in flight
// per CU, 2x R3) and KL tail-fills as A retires. global_load_lds staging is
// LOAD-BEARING for LLC residency (R2: plain loads blew FETCH 24->137 MB).
// blocks [0,512):     A1 (opt_t1/opt_t2/sar_t2 -> diff-map partials)
// blocks [512,1024):  A2 (student/teacher stats + channel sums + ssq sums)
// blocks [1024,2048): KL  (block 1024 arms the kernC counters)
__global__ __launch_bounds__(128) void kernBIG(
    const float* __restrict__ o1p, const float* __restrict__ o2p,
    const float* __restrict__ srp,
    const float* __restrict__ stu, const float* __restrict__ tea,
    const float* __restrict__ so,  const float* __restrict__ to,
    const float* __restrict__ mk,
    float* __restrict__ ws)
{
  const int bid = blockIdx.x;
  const int tid = threadIdx.x, lane = tid & 63, w = tid >> 6;
  __shared__ float sb[3][3][512];    // 18 KB staging (A1: 3 streams; A2: 2)
  __shared__ float gred[2][2];

  if (bid < 512) {
    // ---------------- A1: diff maps ----------------
    const int b   = bid >> 6;          // image (64 blocks per image)
    const int r   = bid & 63;
    const int wdw = r >> 3;            // 512-px window (0..7)
    const int cs  = r & 7;             // 32-channel slice
    const int c0  = cs * 32;
    const size_t base = ((size_t)(b * CCH + c0)) * HWPX + wdw * 512 + lane * 4;
    const int wo = w * 256;            // this wave's LDS slice

#define STAGE1(d, step) { \
    const size_t o = base + (size_t)(step) * HWPX; \
    async16(o1p + o, &sb[d][0][wo]); \
    async16(o2p + o, &sb[d][1][wo]); \
    async16(srp + o, &sb[d][2][wo]); }

    STAGE1(0, 0) STAGE1(1, 1) STAGE1(2, 2)

    float4 l2a = {0,0,0,0}, ca = {0,0,0,0}, l2b = {0,0,0,0}, cb = {0,0,0,0};
    int d = 0;
    for (int s = 0; s < 32; ++s) {
      if (s <= 29)      WAITVM(6);     // step s's 3 loads done (<=9 outstanding)
      else if (s == 30) WAITVM(3);
      else              WAITVM(0);
      __builtin_amdgcn_sched_barrier(0);
      const float4 Av = *(const float4*)&sb[d][0][tid * 4];
      const float4 Bv = *(const float4*)&sb[d][1][tid * 4];
      const float4 Cv = *(const float4*)&sb[d][2][tid * 4];
      upd1(Av, Bv, Cv, l2a, ca, l2b, cb);
      if (s + 3 < 32) STAGE1(d, s + 3);
      d = (d == 2) ? 0 : d + 1;
    }
#undef STAGE1

    const int gp4 = b * HWPX + wdw * 512 + tid * 4;
    float* pa = ws + A1P_OFF;
    *(float4*)&pa[(0 * 8 + cs) * NPIX + gp4] = l2a;
    *(float4*)&pa[(1 * 8 + cs) * NPIX + gp4] = ca;
    *(float4*)&pa[(2 * 8 + cs) * NPIX + gp4] = l2b;
    *(float4*)&pa[(3 * 8 + cs) * NPIX + gp4] = cb;

  } else if (bid < 1024) {
    // ---------------- A2: student/teacher stats + channel sums ----------------
    const int bidA = bid - 512;
    const int b   = bidA >> 6;
    const int r   = bidA & 63;
    const int wdw = r >> 3;
    const int cs  = r & 7;
    const int c0  = cs * 32;
    const size_t base = ((size_t)(b * CCH + c0)) * HWPX + wdw * 512 + lane * 4;
    const int wo = w * 256;

#define STAGE2(d, step) { \
    const size_t o = base + (size_t)(step) * HWPX; \
    async16(stu + o, &sb[d][0][wo]); \
    async16(tea + o, &sb[d][1][wo]); }

    STAGE2(0, 0) STAGE2(1, 1) STAGE2(2, 2)

    float4 ssq = {0,0,0,0}, ssm = {0,0,0,0}, tsm = {0,0,0,0};
    float4 smx = {-INFINITY,-INFINITY,-INFINITY,-INFINITY};
    float4 tmx = smx;
    int d = 0;
    for (int s = 0; s < 32; ++s) {
      if (s <= 29)      WAITVM(4);     // step s's 2 loads done (<=6 outstanding)
      else if (s == 30) WAITVM(2);
      else              WAITVM(0);
      __builtin_amdgcn_sched_barrier(0);
      const float4 Sv = *(const float4*)&sb[d][0][tid * 4];
      const float4 Tv = *(const float4*)&sb[d][1][tid * 4];
      upd2(Sv, Tv, ssq, ssm, smx, tsm, tmx);
      // per-(b,c) window sums (this channel); slot = wdw*2 + wave
      float csm = (Sv.x + Sv.y) + (Sv.z + Sv.w);
      float ctm = (Tv.x + Tv.y) + (Tv.z + Tv.w);
      csm = wred(csm); ctm = wred(ctm);
      if (lane == 0) {
        const int bc = b * CCH + c0 + s;
        ws[CHS_OFF + bc * 16 + wdw * 2 + w] = csm;
        ws[CHT_OFF + bc * 16 + wdw * 2 + w] = ctm;
      }
      if (s + 3 < 32) STAGE2(d, s + 3);
      d = (d == 2) ? 0 : d + 1;
    }
#undef STAGE2

    const int gp4 = b * HWPX + wdw * 512 + tid * 4;
    float* pa = ws + A2P_OFF;
    *(float4*)&pa[(0 * 8 + cs) * NPIX + gp4] = ssm;
    *(float4*)&pa[(1 * 8 + cs) * NPIX + gp4] = smx;
    *(float4*)&pa[(2 * 8 + cs) * NPIX + gp4] = tsm;
    *(float4*)&pa[(3 * 8 + cs) * NPIX + gp4] = tmx;

    // ssq folded to block scalars: global (plain) + local (mask^2-weighted).
    const float4 mv4 = *(const float4*)(mk + b * HWPX + wdw * 512 + tid * 4);
    float g0 = (ssq.x + ssq.y) + (ssq.z + ssq.w);
    float g1 = mv4.x * mv4.x * ssq.x + mv4.y * mv4.y * ssq.y
             + mv4.z * mv4.z * ssq.z + mv4.w * mv4.w * ssq.w;
    g0 = wred(g0); g1 = wred(g1);
    if (lane == 0) { gred[w][0] = g0; gred[w][1] = g1; }
    __syncthreads();
    if (tid == 0) {
      ws[GQ0_OFF + bidA] = gred[0][0] + gred[1][0];
      ws[GQ1_OFF + bidA] = gred[0][1] + gred[1][1];
    }

  } else {
    // ---------------- KL: 2-way softmax KL + class1 MSE ----------------
    const int bkl = bid - 1024;                // 0..1023
    if (bkl == 0 && tid == 0) {                // arm kernC's two counters
      ((unsigned*)(ws + CNT_OFF))[0] = 0u;
      ((unsigned*)(ws + CNT_OFF))[1] = 0u;
    }
    const int gid = bkl * 128 + tid;
    const int p4 = gid << 2;
    const int b  = p4 >> 16;
    const int pp = p4 & 65535;
    const int i0 = b * 131072 + pp;

    const float4 s0 = *(const float4*)(so + i0);
    const float4 s1 = *(const float4*)(so + i0 + 65536);
    const float4 t0 = *(const float4*)(to + i0);
    const float4 t1 = *(const float4*)(to + i0 + 65536);

    float kl = 0.f, c1 = 0.f;
#define KLC(S0, S1, T0, T1)                                           \
    {                                                                 \
      float xs = (S1 - S0) * 0.25f;                                   \
      float xt = (T1 - T0) * 0.25f;                                   \
      float lzs = fmaxf(xs, 0.f) + log1pf(expf(-fabsf(xs)));          \
      float lzt = fmaxf(xt, 0.f) + log1pf(expf(-fabsf(xt)));          \
      float ls0 = -lzs, ls1 = xs - lzs;                               \
      float lt0 = -lzt, lt1 = xt - lzt;                               \
      float pt0 = expf(lt0), pt1 = expf(lt1);                         \
      kl += pt0 * (lt0 - ls0) + pt1 * (lt1 - ls1);                    \
      float ps1 = expf(ls1);                                          \
      float dd = ps1 - pt1;                                           \
      c1 += dd * dd;                                                  \
    }
    KLC(s0.x, s1.x, t0.x, t1.x)
    KLC(s0.y, s1.y, t0.y, t1.y)
    KLC(s0.z, s1.z, t0.z, t1.z)
    KLC(s0.w, s1.w, t0.w, t1.w)
#undef KLC

    kl = wred(kl);
    c1 = wred(c1);
    if (lane == 0) { gred[w][0] = kl; gred[w][1] = c1; }
    __syncthreads();
    if (tid == 0) {
      ws[KLP_OFF + bkl] = gred[0][0] + gred[1][0];
      ws[CL1_OFF + bkl] = gred[0][1] + gred[1][1];
    }
  }
}

// ---------- Kernel C: combine + maps-in-registers + two-level ticket ---------
// 128 blocks (all trivially co-resident on 256 CUs -> spin is deadlock-safe).
// Level 1: all blocks publish GP2 (slice sum of opt_d), spin to 128, then all
// compute mean-dependent terms with od/hd/ssp/tsp still in registers.
// Level 2: publish phase-2 partials; last block (prev==127) does final combine.
__global__ __launch_bounds__(256) void kernC(float* __restrict__ ws,
                                             float* __restrict__ out)
{
  const int tid = threadIdx.x, w = tid >> 6;
  const int slice = blockIdx.x;
  const int gp = slice * 256 + tid;
  unsigned* cnt0 = (unsigned*)(ws + CNT_OFF);
  unsigned* cnt1 = cnt0 + 1;
  __shared__ float red[4][4];
  __shared__ float sm[4];
  __shared__ bool isLast;

  // ---- C1 part: cross-slice combine (maps stay in registers) ----
  const float* pA = ws + A1P_OFF;
  const float* pB = ws + A2P_OFF;
  float a0 = 0.f, a1 = 0.f, a2 = 0.f, a3 = 0.f;
  float b1 = 0.f, b3 = 0.f;
  float m2 = -INFINITY, m4 = -INFINITY;
#pragma unroll
  for (int s = 0; s < 8; ++s) {
    a0 += pA[(0 * 8 + s) * NPIX + gp];
    a1 += pA[(1 * 8 + s) * NPIX + gp];
    a2 += pA[(2 * 8 + s) * NPIX + gp];
    a3 += pA[(3 * 8 + s) * NPIX + gp];
    b1 += pB[(0 * 8 + s) * NPIX + gp];
    m2 = fmaxf(m2, pB[(1 * 8 + s) * NPIX + gp]);
    b3 += pB[(2 * 8 + s) * NPIX + gp];
    m4 = fmaxf(m4, pB[(3 * 8 + s) * NPIX + gp]);
  }

  const float l2o = sqrtf(a0 + 1e-6f);
  const float od  = (l2o + 1.0f - a1 * (1.0f / 256.0f)) * sigmoidf_(l2o * 5.0f);
  const float l2h = sqrtf(a2 + 1e-6f);
  const float hd  = (l2h + 1.0f - a3 * (1.0f / 256.0f)) * sigmoidf_(l2h * 5.0f);
  const float ssp = sigmoidf_(b1 * (1.0f / 256.0f) + m2);
  const float tsp = sigmoidf_(b3 * (1.0f / 256.0f) + m4);

  float r2 = wred(od);
  if ((tid & 63) == 0) red[w][0] = r2;
  __syncthreads();
  if (tid == 0) {
    __hip_atomic_store(ws + GP2_OFF + slice,
                       red[0][0] + red[1][0] + red[2][0] + red[3][0],
                       __ATOMIC_RELAXED, __HIP_MEMORY_SCOPE_AGENT);
    __threadfence();
    __hip_atomic_fetch_add(cnt0, 1u, __ATOMIC_ACQ_REL, __HIP_MEMORY_SCOPE_AGENT);
    while (__hip_atomic_load(cnt0, __ATOMIC_RELAXED,
                             __HIP_MEMORY_SCOPE_AGENT) < 128u)
      __builtin_amdgcn_s_sleep(1);
  }
  __syncthreads();
  __threadfence();

  // ---- C2D part: mean-dependent terms ----
  float v = (tid < 128)
      ? __hip_atomic_load(ws + GP2_OFF + tid, __ATOMIC_RELAXED,
                          __HIP_MEMORY_SCOPE_AGENT)
      : 0.f;
  v = wred(v);
  if ((tid & 63) == 0) sm[w] = v;
  __syncthreads();
  const float mean_opt = (sm[0] + sm[1] + sm[2] + sm[3]) * (1.0f / 32768.0f);
  const float att_w = sigmoidf_(mean_opt * 10.0f);
  const float thr = mean_opt * 1.5f;

  const float mask = od > thr ? 1.0f : 0.0f;
  const float wgt = mask * 2.0f + (1.0f - mask) * 0.5f;
  float dt = (hd - od) * wgt; dt *= dt;
  const float amp = 1.0f + att_w * mask;
  float st = (ssp - tsp) * amp; st *= st;

  float cf = 0.f, catt = 0.f;
  if (gp < NCHAN) {
    float s = 0.f, t = 0.f;
#pragma unroll
    for (int k = 0; k < 16; ++k) {
      s += ws[CHS_OFF + gp * 16 + k];
      t += ws[CHT_OFF + gp * 16 + k];
    }
    const float smn = s * (1.0f / 4096.0f);
    const float tmn = t * (1.0f / 4096.0f);
    const float dch = smn - tmn;
    cf = dch * dch;
    const float d2 = sigmoidf_(smn) - sigmoidf_(tmn);
    catt = d2 * d2;
  }

  dt = wred(dt); st = wred(st); cf = wred(cf); catt = wred(catt);
  __syncthreads();                           // red[] reuse
  if ((tid & 63) == 0) { red[w][0] = dt; red[w][1] = st; red[w][2] = cf; red[w][3] = catt; }
  __syncthreads();
  if (tid == 0) {
    __hip_atomic_store(ws + DTP_OFF + slice,
                       red[0][0] + red[1][0] + red[2][0] + red[3][0],
                       __ATOMIC_RELAXED, __HIP_MEMORY_SCOPE_AGENT);
    __hip_atomic_store(ws + STP_OFF + slice,
                       red[0][1] + red[1][1] + red[2][1] + red[3][1],
                       __ATOMIC_RELAXED, __HIP_MEMORY_SCOPE_AGENT);
    __hip_atomic_store(ws + CFP_OFF + slice,
                       red[0][2] + red[1][2] + red[2][2] + red[3][2],
                       __ATOMIC_RELAXED, __HIP_MEMORY_SCOPE_AGENT);
    __hip_atomic_store(ws + CAP_OFF + slice,
                       red[0][3] + red[1][3] + red[2][3] + red[3][3],
                       __ATOMIC_RELAXED, __HIP_MEMORY_SCOPE_AGENT);
    __threadfence();
    unsigned prev = __hip_atomic_fetch_add(cnt1, 1u, __ATOMIC_ACQ_REL,
                                           __HIP_MEMORY_SCOPE_AGENT);
    isLast = (prev == 127u);
  }
  __syncthreads();
  if (!isLast) return;
  __threadfence();

  // ---- last block performs the final combine ----
  auto bsum = [&](int off, int n) -> float {
    float acc = 0.f;
    for (int i = tid; i < n; i += 256)
      acc += __hip_atomic_load(ws + off + i, __ATOMIC_RELAXED, __HIP_MEMORY_SCOPE_AGENT);
    acc = wred(acc);
    if ((tid & 63) == 0) sm[tid >> 6] = acc;
    __syncthreads();
    const float r = sm[0] + sm[1] + sm[2] + sm[3];
    __syncthreads();
    return r;
  };

  const float ssqg = bsum(GQ0_OFF, 512);
  const float ssql = bsum(GQ1_OFF, 512);
  const float sopt = bsum(GP2_OFF, 128);
  const float kls  = bsum(KLP_OFF, 1024);
  const float c1s  = bsum(CL1_OFF, 1024);
  const float dts  = bsum(DTP_OFF, 128);
  const float sts  = bsum(STP_OFF, 128);
  const float cfs  = bsum(CFP_OFF, 128);
  const float cas  = bsum(CAP_OFF, 128);

  if (tid == 0) {
    const float global_loss = ssqg * (1.0f / (float)NFEAT);
    const float local_loss  = ssql * (1.0f / (float)NFEAT);
    const float chan_f      = cfs * (1.0f / (float)NCHAN);
    const float feat = 0.3f * global_loss + 0.5f * local_loss + 0.2f * chan_f;

    const float kl = kls * 2.0f;                 // * T^2 / B = 16/8
    const float c1 = c1s * (2.0f / 524288.0f);
    const float outl = kl + c1;

    const float mo = sopt * (1.0f / 32768.0f);
    const float aw = sigmoidf_(mo * 10.0f);
    const float diff_loss = dts * (1.0f / 32768.0f);
    const float spat_loss = sts * (1.0f / 32768.0f);
    const float chan_att  = cas * (1.0f / (float)NCHAN);

    const float alpha = 0.5f * (1.0f + 0.5f * aw);
    const float beta  = 0.3f * (1.0f - 0.3f * aw);
    const float gamma = 0.2f * (1.0f + 0.5f * aw);
    const float datt = alpha * diff_loss + beta * chan_att + gamma * spat_loss;

    const float total = 0.3f * feat + 0.4f * outl + 0.3f * datt;
    out[0] = total;
    out[1] = feat;
    out[2] = outl;
    out[3] = datt;
  }
}

extern "C" void kernel_launch(void* const* d_in, const int* in_sizes, int n_in,
                              void* d_out, int out_size, void* d_ws, size_t ws_size,
                              hipStream_t stream)
{
  const float* stu = (const float*)d_in[0];
  const float* tea = (const float*)d_in[1];
  const float* so  = (const float*)d_in[2];
  const float* to  = (const float*)d_in[3];
  const float* o1  = (const float*)d_in[4];
  const float* o2  = (const float*)d_in[5];
  const float* sr  = (const float*)d_in[6];
  const float* mk  = (const float*)d_in[7];
  float* ws  = (float*)d_ws;
  float* out = (float*)d_out;

  kernBIG<<<2048, 128, 0, stream>>>(o1, o2, sr, stu, tea, so, to, mk, ws);
  kernC<<<128, 256, 0, stream>>>(ws, out);
}

// Round 5
// 201.863 us; speedup vs baseline: 1.4473x; 1.0109x over previous
//
#include <hip/hip_runtime.h>
#include <math.h>

// Geometry: features [B=8,C=256,H=64,W=64]; outputs [8,2,256,256]
#define HWPX  4096
#define CCH   256
#define NPIX  32768
#define NCHAN 2048
#define NFEAT 8388608
#define NSLI  16                            // channel slices (16 ch each)

// Workspace layout (floats). Every cell written before read; counters armed
// inside kernBIG (first KL block), read only by kernC (next dispatch).
#define A1P_OFF   0                         // 4q x 16slices x NPIX (A1 partials)
#define A2P_OFF   (A1P_OFF + 4*NSLI*NPIX)   // 4q x 16slices x NPIX (A2 partials)
#define CHS_OFF   (A2P_OFF + 4*NSLI*NPIX)   // 2048 bc x 16 slots (4 wdw x 4 waves)
#define CHT_OFF   (CHS_OFF + NCHAN*16)
#define KLP_OFF   (CHT_OFF + NCHAN*16)      // 512 block partials (KL)
#define CL1_OFF   (KLP_OFF + 512)
#define GQ0_OFF   (CL1_OFF + 512)           // 512 (A2 block sums: global ssq)
#define GQ1_OFF   (GQ0_OFF + 512)           // 512 (A2 block sums: masked ssq)
#define GP2_OFF   (GQ1_OFF + 512)           // 128 (kernC slice sums of opt_d)
#define DTP_OFF   (GP2_OFF + 128)           // 128 (kernC phase-2 partials)
#define STP_OFF   (DTP_OFF + 128)
#define CFP_OFF   (STP_OFF + 128)
#define CAP_OFF   (CFP_OFF + 128)
#define CNT_OFF   (CAP_OFF + 128)           // 2 counters (armed by kernBIG)

// s_waitcnt with vmcnt(N), lgkm/exp unconstrained (gfx9 encoding)
#define WAITVM(N) __builtin_amdgcn_s_waitcnt(0xF70 | (N))

__device__ __forceinline__ void async16(const float* g, float* l) {
  __builtin_amdgcn_global_load_lds(
      (const __attribute__((address_space(1))) void*)g,
      (__attribute__((address_space(3))) void*)l, 16, 0, 0);
}

__device__ __forceinline__ float sigmoidf_(float x) { return 1.0f / (1.0f + expf(-x)); }

__device__ __forceinline__ float wred(float v) {
#pragma unroll
  for (int o = 32; o > 0; o >>= 1) v += __shfl_down(v, o, 64);
  return v;
}

__device__ __forceinline__ void upd1(const float4& A, const float4& B, const float4& C,
                                     float4& l2a, float4& ca, float4& l2b, float4& cb)
{
#define U1(K) { \
  float d = A.K - B.K; l2a.K = fmaf(d, d, l2a.K); \
  float p = A.K * B.K; \
  float den = fmaxf(fabsf(A.K) * fabsf(B.K), 1e-8f); \
  ca.K = fmaf(p, __builtin_amdgcn_rcpf(den), ca.K); \
  float d2 = A.K - C.K; l2b.K = fmaf(d2, d2, l2b.K); \
  float p2 = A.K * C.K; \
  float dn2 = fmaxf(fabsf(A.K) * fabsf(C.K), 1e-8f); \
  cb.K = fmaf(p2, __builtin_amdgcn_rcpf(dn2), cb.K); }
  U1(x) U1(y) U1(z) U1(w)
#undef U1
}

__device__ __forceinline__ void upd2(const float4& S, const float4& T,
                                     float4& ssq, float4& ssm, float4& smx,
                                     float4& tsm, float4& tmx)
{
#define U2(K) { \
  float ds = S.K - T.K; ssq.K = fmaf(ds, ds, ssq.K); \
  ssm.K += S.K; tsm.K += T.K; \
  smx.K = fmaxf(smx.K, S.K); tmx.K = fmaxf(tmx.K, T.K); }
  U2(x) U2(y) U2(z) U2(w)
#undef U2
}

// ---------- Kernel BIG: A1 | A2 | KL by block range --------------------------
// 256-thread blocks, 1024-px windows (4 KB rows: LLC-friendly -- R4 showed
// 2 KB rows double HBM FETCH), 16-channel slices -> 512 A1 + 512 A2 blocks.
// 36 KB LDS -> 4 blocks/CU -> 1024 resident slots: ALL 1024 A-blocks resident
// at t=0 (16 A-waves/CU, 2x R3 concurrency); 512 KL blocks tail-fill.
// global_load_lds staging is LOAD-BEARING for LLC residency (R2: plain loads
// blew FETCH 24->137 MB). Depth-3 per-wave async pipeline, zero barriers.
// blocks [0,512):     A1 (opt_t1/opt_t2/sar_t2 -> diff-map partials)
// blocks [512,1024):  A2 (student/teacher stats + channel sums + ssq sums)
// blocks [1024,1536): KL  (block 1024 arms the kernC counters)
__global__ __launch_bounds__(256) void kernBIG(
    const float* __restrict__ o1p, const float* __restrict__ o2p,
    const float* __restrict__ srp,
    const float* __restrict__ stu, const float* __restrict__ tea,
    const float* __restrict__ so,  const float* __restrict__ to,
    const float* __restrict__ mk,
    float* __restrict__ ws)
{
  const int bid = blockIdx.x;
  const int tid = threadIdx.x, lane = tid & 63, w = tid >> 6;
  __shared__ float sb[3][3][1024];   // 36 KB staging (A1: 3 streams; A2: 2)
  __shared__ float gred[4][2];

  if (bid < 512) {
    // ---------------- A1: diff maps ----------------
    const int b   = bid >> 6;          // image (64 blocks per image)
    const int r   = bid & 63;
    const int wdw = r >> 4;            // 1024-px window (0..3)
    const int cs  = r & 15;            // 16-channel slice
    const int c0  = cs * 16;
    const size_t base = ((size_t)(b * CCH + c0)) * HWPX + wdw * 1024 + lane * 4;
    const int wo = w * 256;            // this wave's LDS slice

#define STAGE1(d, step) { \
    const size_t o = base + (size_t)(step) * HWPX; \
    async16(o1p + o, &sb[d][0][wo]); \
    async16(o2p + o, &sb[d][1][wo]); \
    async16(srp + o, &sb[d][2][wo]); }

    STAGE1(0, 0) STAGE1(1, 1) STAGE1(2, 2)

    float4 l2a = {0,0,0,0}, ca = {0,0,0,0}, l2b = {0,0,0,0}, cb = {0,0,0,0};
    int d = 0;
    for (int s = 0; s < 16; ++s) {
      if (s <= 13)      WAITVM(6);     // step s's 3 loads done (<=9 outstanding)
      else if (s == 14) WAITVM(3);
      else              WAITVM(0);
      __builtin_amdgcn_sched_barrier(0);
      const float4 Av = *(const float4*)&sb[d][0][tid * 4];
      const float4 Bv = *(const float4*)&sb[d][1][tid * 4];
      const float4 Cv = *(const float4*)&sb[d][2][tid * 4];
      upd1(Av, Bv, Cv, l2a, ca, l2b, cb);
      if (s + 3 < 16) STAGE1(d, s + 3);
      d = (d == 2) ? 0 : d + 1;
    }
#undef STAGE1

    const int gp4 = b * HWPX + wdw * 1024 + tid * 4;
    float* pa = ws + A1P_OFF;
    *(float4*)&pa[(0 * NSLI + cs) * NPIX + gp4] = l2a;
    *(float4*)&pa[(1 * NSLI + cs) * NPIX + gp4] = ca;
    *(float4*)&pa[(2 * NSLI + cs) * NPIX + gp4] = l2b;
    *(float4*)&pa[(3 * NSLI + cs) * NPIX + gp4] = cb;

  } else if (bid < 1024) {
    // ---------------- A2: student/teacher stats + channel sums ----------------
    const int bidA = bid - 512;
    const int b   = bidA >> 6;
    const int r   = bidA & 63;
    const int wdw = r >> 4;
    const int cs  = r & 15;
    const int c0  = cs * 16;
    const size_t base = ((size_t)(b * CCH + c0)) * HWPX + wdw * 1024 + lane * 4;
    const int wo = w * 256;

#define STAGE2(d, step) { \
    const size_t o = base + (size_t)(step) * HWPX; \
    async16(stu + o, &sb[d][0][wo]); \
    async16(tea + o, &sb[d][1][wo]); }

    STAGE2(0, 0) STAGE2(1, 1) STAGE2(2, 2)

    float4 ssq = {0,0,0,0}, ssm = {0,0,0,0}, tsm = {0,0,0,0};
    float4 smx = {-INFINITY,-INFINITY,-INFINITY,-INFINITY};
    float4 tmx = smx;
    int d = 0;
    for (int s = 0; s < 16; ++s) {
      if (s <= 13)      WAITVM(4);     // step s's 2 loads done (<=6 outstanding)
      else if (s == 14) WAITVM(2);
      else              WAITVM(0);
      __builtin_amdgcn_sched_barrier(0);
      const float4 Sv = *(const float4*)&sb[d][0][tid * 4];
      const float4 Tv = *(const float4*)&sb[d][1][tid * 4];
      upd2(Sv, Tv, ssq, ssm, smx, tsm, tmx);
      // per-(b,c) window sums (this channel); slot = wdw*4 + wave
      float csm = (Sv.x + Sv.y) + (Sv.z + Sv.w);
      float ctm = (Tv.x + Tv.y) + (Tv.z + Tv.w);
      csm = wred(csm); ctm = wred(ctm);
      if (lane == 0) {
        const int bc = b * CCH + c0 + s;
        ws[CHS_OFF + bc * 16 + wdw * 4 + w] = csm;
        ws[CHT_OFF + bc * 16 + wdw * 4 + w] = ctm;
      }
      if (s + 3 < 16) STAGE2(d, s + 3);
      d = (d == 2) ? 0 : d + 1;
    }
#undef STAGE2

    const int gp4 = b * HWPX + wdw * 1024 + tid * 4;
    float* pa = ws + A2P_OFF;
    *(float4*)&pa[(0 * NSLI + cs) * NPIX + gp4] = ssm;
    *(float4*)&pa[(1 * NSLI + cs) * NPIX + gp4] = smx;
    *(float4*)&pa[(2 * NSLI + cs) * NPIX + gp4] = tsm;
    *(float4*)&pa[(3 * NSLI + cs) * NPIX + gp4] = tmx;

    // ssq folded to block scalars: global (plain) + local (mask^2-weighted).
    const float4 mv4 = *(const float4*)(mk + b * HWPX + wdw * 1024 + tid * 4);
    float g0 = (ssq.x + ssq.y) + (ssq.z + ssq.w);
    float g1 = mv4.x * mv4.x * ssq.x + mv4.y * mv4.y * ssq.y
             + mv4.z * mv4.z * ssq.z + mv4.w * mv4.w * ssq.w;
    g0 = wred(g0); g1 = wred(g1);
    if (lane == 0) { gred[w][0] = g0; gred[w][1] = g1; }
    __syncthreads();
    if (tid == 0) {
      ws[GQ0_OFF + bidA] = gred[0][0] + gred[1][0] + gred[2][0] + gred[3][0];
      ws[GQ1_OFF + bidA] = gred[0][1] + gred[1][1] + gred[2][1] + gred[3][1];
    }

  } else {
    // ---------------- KL: 2-way softmax KL + class1 MSE ----------------
    const int bkl = bid - 1024;                // 0..511
    if (bkl == 0 && tid == 0) {                // arm kernC's two counters
      ((unsigned*)(ws + CNT_OFF))[0] = 0u;
      ((unsigned*)(ws + CNT_OFF))[1] = 0u;
    }
    const int gid = bkl * 256 + tid;
    const int p4 = gid << 2;
    const int b  = p4 >> 16;
    const int pp = p4 & 65535;
    const int i0 = b * 131072 + pp;

    const float4 s0 = *(const float4*)(so + i0);
    const float4 s1 = *(const float4*)(so + i0 + 65536);
    const float4 t0 = *(const float4*)(to + i0);
    const float4 t1 = *(const float4*)(to + i0 + 65536);

    float kl = 0.f, c1 = 0.f;
#define KLC(S0, S1, T0, T1)                                           \
    {                                                                 \
      float xs = (S1 - S0) * 0.25f;                                   \
      float xt = (T1 - T0) * 0.25f;                                   \
      float lzs = fmaxf(xs, 0.f) + log1pf(expf(-fabsf(xs)));          \
      float lzt = fmaxf(xt, 0.f) + log1pf(expf(-fabsf(xt)));          \
      float ls0 = -lzs, ls1 = xs - lzs;                               \
      float lt0 = -lzt, lt1 = xt - lzt;                               \
      float pt0 = expf(lt0), pt1 = expf(lt1);                         \
      kl += pt0 * (lt0 - ls0) + pt1 * (lt1 - ls1);                    \
      float ps1 = expf(ls1);                                          \
      float dd = ps1 - pt1;                                           \
      c1 += dd * dd;                                                  \
    }
    KLC(s0.x, s1.x, t0.x, t1.x)
    KLC(s0.y, s1.y, t0.y, t1.y)
    KLC(s0.z, s1.z, t0.z, t1.z)
    KLC(s0.w, s1.w, t0.w, t1.w)
#undef KLC

    kl = wred(kl);
    c1 = wred(c1);
    if (lane == 0) { gred[w][0] = kl; gred[w][1] = c1; }
    __syncthreads();
    if (tid == 0) {
      ws[KLP_OFF + bkl] = gred[0][0] + gred[1][0] + gred[2][0] + gred[3][0];
      ws[CL1_OFF + bkl] = gred[0][1] + gred[1][1] + gred[2][1] + gred[3][1];
    }
  }
}

// ---------- Kernel C: combine + maps-in-registers + two-level ticket ---------
// 128 blocks (all trivially co-resident on 256 CUs -> spin is deadlock-safe).
// Level 1: all blocks publish GP2 (slice sum of opt_d), spin to 128, then all
// compute mean-dependent terms with od/hd/ssp/tsp still in registers.
// Level 2: publish phase-2 partials; last block (prev==127) does final combine.
__global__ __launch_bounds__(256) void kernC(float* __restrict__ ws,
                                             float* __restrict__ out)
{
  const int tid = threadIdx.x, w = tid >> 6;
  const int slice = blockIdx.x;
  const int gp = slice * 256 + tid;
  unsigned* cnt0 = (unsigned*)(ws + CNT_OFF);
  unsigned* cnt1 = cnt0 + 1;
  __shared__ float red[4][4];
  __shared__ float sm[4];
  __shared__ bool isLast;

  // ---- C1 part: cross-slice combine (maps stay in registers) ----
  const float* pA = ws + A1P_OFF;
  const float* pB = ws + A2P_OFF;
  float a0 = 0.f, a1 = 0.f, a2 = 0.f, a3 = 0.f;
  float b1 = 0.f, b3 = 0.f;
  float m2 = -INFINITY, m4 = -INFINITY;
#pragma unroll
  for (int s = 0; s < NSLI; ++s) {
    a0 += pA[(0 * NSLI + s) * NPIX + gp];
    a1 += pA[(1 * NSLI + s) * NPIX + gp];
    a2 += pA[(2 * NSLI + s) * NPIX + gp];
    a3 += pA[(3 * NSLI + s) * NPIX + gp];
    b1 += pB[(0 * NSLI + s) * NPIX + gp];
    m2 = fmaxf(m2, pB[(1 * NSLI + s) * NPIX + gp]);
    b3 += pB[(2 * NSLI + s) * NPIX + gp];
    m4 = fmaxf(m4, pB[(3 * NSLI + s) * NPIX + gp]);
  }

  const float l2o = sqrtf(a0 + 1e-6f);
  const float od  = (l2o + 1.0f - a1 * (1.0f / 256.0f)) * sigmoidf_(l2o * 5.0f);
  const float l2h = sqrtf(a2 + 1e-6f);
  const float hd  = (l2h + 1.0f - a3 * (1.0f / 256.0f)) * sigmoidf_(l2h * 5.0f);
  const float ssp = sigmoidf_(b1 * (1.0f / 256.0f) + m2);
  const float tsp = sigmoidf_(b3 * (1.0f / 256.0f) + m4);

  float r2 = wred(od);
  if ((tid & 63) == 0) red[w][0] = r2;
  __syncthreads();
  if (tid == 0) {
    __hip_atomic_store(ws + GP2_OFF + slice,
                       red[0][0] + red[1][0] + red[2][0] + red[3][0],
                       __ATOMIC_RELAXED, __HIP_MEMORY_SCOPE_AGENT);
    __threadfence();
    __hip_atomic_fetch_add(cnt0, 1u, __ATOMIC_ACQ_REL, __HIP_MEMORY_SCOPE_AGENT);
    while (__hip_atomic_load(cnt0, __ATOMIC_RELAXED,
                             __HIP_MEMORY_SCOPE_AGENT) < 128u)
      __builtin_amdgcn_s_sleep(1);
  }
  __syncthreads();
  __threadfence();

  // ---- C2D part: mean-dependent terms ----
  float v = (tid < 128)
      ? __hip_atomic_load(ws + GP2_OFF + tid, __ATOMIC_RELAXED,
                          __HIP_MEMORY_SCOPE_AGENT)
      : 0.f;
  v = wred(v);
  if ((tid & 63) == 0) sm[w] = v;
  __syncthreads();
  const float mean_opt = (sm[0] + sm[1] + sm[2] + sm[3]) * (1.0f / 32768.0f);
  const float att_w = sigmoidf_(mean_opt * 10.0f);
  const float thr = mean_opt * 1.5f;

  const float mask = od > thr ? 1.0f : 0.0f;
  const float wgt = mask * 2.0f + (1.0f - mask) * 0.5f;
  float dt = (hd - od) * wgt; dt *= dt;
  const float amp = 1.0f + att_w * mask;
  float st = (ssp - tsp) * amp; st *= st;

  float cf = 0.f, catt = 0.f;
  if (gp < NCHAN) {
    float s = 0.f, t = 0.f;
#pragma unroll
    for (int k = 0; k < 16; ++k) {
      s += ws[CHS_OFF + gp * 16 + k];
      t += ws[CHT_OFF + gp * 16 + k];
    }
    const float smn = s * (1.0f / 4096.0f);
    const float tmn = t * (1.0f / 4096.0f);
    const float dch = smn - tmn;
    cf = dch * dch;
    const float d2 = sigmoidf_(smn) - sigmoidf_(tmn);
    catt = d2 * d2;
  }

  dt = wred(dt); st = wred(st); cf = wred(cf); catt = wred(catt);
  __syncthreads();                           // red[] reuse
  if ((tid & 63) == 0) { red[w][0] = dt; red[w][1] = st; red[w][2] = cf; red[w][3] = catt; }
  __syncthreads();
  if (tid == 0) {
    __hip_atomic_store(ws + DTP_OFF + slice,
                       red[0][0] + red[1][0] + red[2][0] + red[3][0],
                       __ATOMIC_RELAXED, __HIP_MEMORY_SCOPE_AGENT);
    __hip_atomic_store(ws + STP_OFF + slice,
                       red[0][1] + red[1][1] + red[2][1] + red[3][1],
                       __ATOMIC_RELAXED, __HIP_MEMORY_SCOPE_AGENT);
    __hip_atomic_store(ws + CFP_OFF + slice,
                       red[0][2] + red[1][2] + red[2][2] + red[3][2],
                       __ATOMIC_RELAXED, __HIP_MEMORY_SCOPE_AGENT);
    __hip_atomic_store(ws + CAP_OFF + slice,
                       red[0][3] + red[1][3] + red[2][3] + red[3][3],
                       __ATOMIC_RELAXED, __HIP_MEMORY_SCOPE_AGENT);
    __threadfence();
    unsigned prev = __hip_atomic_fetch_add(cnt1, 1u, __ATOMIC_ACQ_REL,
                                           __HIP_MEMORY_SCOPE_AGENT);
    isLast = (prev == 127u);
  }
  __syncthreads();
  if (!isLast) return;
  __threadfence();

  // ---- last block performs the final combine ----
  auto bsum = [&](int off, int n) -> float {
    float acc = 0.f;
    for (int i = tid; i < n; i += 256)
      acc += __hip_atomic_load(ws + off + i, __ATOMIC_RELAXED, __HIP_MEMORY_SCOPE_AGENT);
    acc = wred(acc);
    if ((tid & 63) == 0) sm[tid >> 6] = acc;
    __syncthreads();
    const float r = sm[0] + sm[1] + sm[2] + sm[3];
    __syncthreads();
    return r;
  };

  const float ssqg = bsum(GQ0_OFF, 512);
  const float ssql = bsum(GQ1_OFF, 512);
  const float sopt = bsum(GP2_OFF, 128);
  const float kls  = bsum(KLP_OFF, 512);
  const float c1s  = bsum(CL1_OFF, 512);
  const float dts  = bsum(DTP_OFF, 128);
  const float sts  = bsum(STP_OFF, 128);
  const float cfs  = bsum(CFP_OFF, 128);
  const float cas  = bsum(CAP_OFF, 128);

  if (tid == 0) {
    const float global_loss = ssqg * (1.0f / (float)NFEAT);
    const float local_loss  = ssql * (1.0f / (float)NFEAT);
    const float chan_f      = cfs * (1.0f / (float)NCHAN);
    const float feat = 0.3f * global_loss + 0.5f * local_loss + 0.2f * chan_f;

    const float kl = kls * 2.0f;                 // * T^2 / B = 16/8
    const float c1 = c1s * (2.0f / 524288.0f);
    const float outl = kl + c1;

    const float mo = sopt * (1.0f / 32768.0f);
    const float aw = sigmoidf_(mo * 10.0f);
    const float diff_loss = dts * (1.0f / 32768.0f);
    const float spat_loss = sts * (1.0f / 32768.0f);
    const float chan_att  = cas * (1.0f / (float)NCHAN);

    const float alpha = 0.5f * (1.0f + 0.5f * aw);
    const float beta  = 0.3f * (1.0f - 0.3f * aw);
    const float gamma = 0.2f * (1.0f + 0.5f * aw);
    const float datt = alpha * diff_loss + beta * chan_att + gamma * spat_loss;

    const float total = 0.3f * feat + 0.4f * outl + 0.3f * datt;
    out[0] = total;
    out[1] = feat;
    out[2] = outl;
    out[3] = datt;
  }
}

extern "C" void kernel_launch(void* const* d_in, const int* in_sizes, int n_in,
                              void* d_out, int out_size, void* d_ws, size_t ws_size,
                              hipStream_t stream)
{
  const float* stu = (const float*)d_in[0];
  const float* tea = (const float*)d_in[1];
  const float* so  = (const float*)d_in[2];
  const float* to  = (const float*)d_in[3];
  const float* o1  = (const float*)d_in[4];
  const float* o2  = (const float*)d_in[5];
  const float* sr  = (const float*)d_in[6];
  const float* mk  = (const float*)d_in[7];
  float* ws  = (float*)d_ws;
  float* out = (float*)d_out;

  kernBIG<<<1536, 256, 0, stream>>>(o1, o2, sr, stu, tea, so, to, mk, ws);
  kernC<<<128, 256, 0, stream>>>(ws, out);
}